// Round 1
// baseline (323.794 us; speedup 1.0000x reference)
//
#include <hip/hip_runtime.h>
#include <hip/hip_bf16.h>

#define S_LEN 2048
#define D_MODEL 1024
#define NHEAD 16
#define HDIM 64
#define BATCH 2
#define M_TOT (BATCH * S_LEN)   // 4096

typedef __attribute__((ext_vector_type(4))) float f32x4;
typedef __attribute__((ext_vector_type(4))) short s16x4;

__device__ inline short f2bf(float f) {
  unsigned u = __float_as_uint(f);
  unsigned r = (u + 0x7fffu + ((u >> 16) & 1u)) >> 16;
  return (short)r;
}

// ---------------------------------------------------------------------------
// Weight transpose + cast: Wt[n][k] = (bf16) W[k][n]
// grid (32,32), block (32,8)
// ---------------------------------------------------------------------------
__global__ __launch_bounds__(256) void wtrans_k(const float* __restrict__ W,
                                                short* __restrict__ Wt) {
  __shared__ float tile[32][33];
  const int tx = threadIdx.x, ty = threadIdx.y;
  const int n0 = blockIdx.x * 32, k0 = blockIdx.y * 32;
#pragma unroll
  for (int j = 0; j < 4; ++j)
    tile[ty + j * 8][tx] = W[(size_t)(k0 + ty + j * 8) * D_MODEL + n0 + tx];
  __syncthreads();
#pragma unroll
  for (int j = 0; j < 4; ++j)
    Wt[(size_t)(n0 + ty + j * 8) * D_MODEL + k0 + tx] = f2bf(tile[tx][ty + j * 8]);
}

// ---------------------------------------------------------------------------
// GEMM: C[M=4096][N=1024] = A[4096][1024] @ Wt^T + bias
//   AMODE 0: A is fp32 (X), fused cast to bf16 while staging
//   AMODE 1: A is bf16 (attention output)
//   OMODE 0: bf16 out, head-split [b,h,s,d]      (Q, K)
//   OMODE 1: bf16 out, head-split transposed [b,h,d,s]  (V)
//   OMODE 2: fp32 out, plain [m][n]              (final projection)
// block 256 (4 waves), tile 128x128, BK=32, mfma 16x16x16 bf16
// LDS tiles padded to stride 36 elems (72B) -> conflict-free b64 frag reads
// ---------------------------------------------------------------------------
template <int AMODE, int OMODE>
__global__ __launch_bounds__(256) void gemm_k(const void* __restrict__ Ap,
                                              const short* __restrict__ Bt,
                                              const float* __restrict__ bias,
                                              void* __restrict__ Cp) {
  __shared__ short As[128 * 36];
  __shared__ short Bs[128 * 36];
  const int tid = threadIdx.x;
  const int m0 = blockIdx.x * 128;
  const int n0 = blockIdx.y * 128;
  const int w = tid >> 6, lane = tid & 63;
  const int wm = w >> 1, wn = w & 1;
  const int lr = lane & 15, lg = lane >> 4;
  const int r = tid & 127, half = tid >> 7;

  f32x4 acc[4][4] = {};

  for (int k0 = 0; k0 < D_MODEL; k0 += 32) {
    // ---- stage A tile [128][32]
    if (AMODE == 0) {
      const float* A = (const float*)Ap;
      const float4* src =
          (const float4*)(A + (size_t)(m0 + r) * D_MODEL + k0 + half * 16);
#pragma unroll
      for (int j = 0; j < 4; ++j) {
        float4 v = src[j];
        s16x4 p;
        p[0] = f2bf(v.x); p[1] = f2bf(v.y); p[2] = f2bf(v.z); p[3] = f2bf(v.w);
        *(s16x4*)&As[r * 36 + half * 16 + j * 4] = p;
      }
    } else {
      const short* A = (const short*)Ap;
      const short* srow = A + (size_t)(m0 + r) * D_MODEL + k0 + half * 16;
#pragma unroll
      for (int j = 0; j < 2; ++j) {
        int4 v = *(const int4*)(srow + j * 8);
        *(int2*)&As[r * 36 + half * 16 + j * 8] = make_int2(v.x, v.y);
        *(int2*)&As[r * 36 + half * 16 + j * 8 + 4] = make_int2(v.z, v.w);
      }
    }
    // ---- stage B tile [128][32] from Wt rows (contiguous in k)
    {
      const short* srow = Bt + (size_t)(n0 + r) * D_MODEL + k0 + half * 16;
#pragma unroll
      for (int j = 0; j < 2; ++j) {
        int4 v = *(const int4*)(srow + j * 8);
        *(int2*)&Bs[r * 36 + half * 16 + j * 8] = make_int2(v.x, v.y);
        *(int2*)&Bs[r * 36 + half * 16 + j * 8 + 4] = make_int2(v.z, v.w);
      }
    }
    __syncthreads();

#pragma unroll
    for (int ks = 0; ks < 2; ++ks) {
      s16x4 af[4], bfr[4];
#pragma unroll
      for (int i = 0; i < 4; ++i) {
        af[i]  = *(const s16x4*)&As[(wm * 64 + i * 16 + lr) * 36 + ks * 16 + lg * 4];
        bfr[i] = *(const s16x4*)&Bs[(wn * 64 + i * 16 + lr) * 36 + ks * 16 + lg * 4];
      }
#pragma unroll
      for (int mi = 0; mi < 4; ++mi)
#pragma unroll
        for (int ni = 0; ni < 4; ++ni)
          acc[mi][ni] = __builtin_amdgcn_mfma_f32_16x16x16bf16_1k(
              af[mi], bfr[ni], acc[mi][ni], 0, 0, 0);
    }
    __syncthreads();
  }

  // ---- epilogue
#pragma unroll
  for (int ni = 0; ni < 4; ++ni) {
    const int n = n0 + wn * 64 + ni * 16 + lr;
    const float bn = bias[n];
#pragma unroll
    for (int mi = 0; mi < 4; ++mi) {
      const int mb = m0 + wm * 64 + mi * 16 + lg * 4;
      f32x4 v = acc[mi][ni];
      if (OMODE == 2) {
        float* C = (float*)Cp;
#pragma unroll
        for (int j = 0; j < 4; ++j)
          C[(size_t)(mb + j) * D_MODEL + n] = v[j] + bn;
      } else if (OMODE == 0) {
        short* C = (short*)Cp;
#pragma unroll
        for (int j = 0; j < 4; ++j) {
          int m = mb + j;
          int b = m >> 11, s = m & 2047, h = n >> 6, d = n & 63;
          C[((size_t)((b * NHEAD + h) * S_LEN) + s) * HDIM + d] = f2bf(v[j] + bn);
        }
      } else {  // OMODE == 1 : V transposed [b,h,d,s]; 4 regs = 4 consecutive s
        short* C = (short*)Cp;
        int b = mb >> 11, s = mb & 2047, h = n >> 6, d = n & 63;
        s16x4 p;
#pragma unroll
        for (int j = 0; j < 4; ++j) p[j] = f2bf(v[j] + bn);
        *(s16x4*)&C[((size_t)((b * NHEAD + h) * HDIM) + d) * S_LEN + s] = p;
      }
    }
  }
}

// ---------------------------------------------------------------------------
// Flash attention (causal). grid (32 qtiles, 32 bh), block 256 (4 waves).
// Wave w owns q rows q0+16w .. +15. S^T = K @ Q^T so softmax fragment layout
// feeds PV's B operand directly. Online softmax in fp32.
// Q,K: [bh][2048][64]; Vt: [bh][64][2048]; AO: [4096][1024] bf16.
// ---------------------------------------------------------------------------
__global__ __launch_bounds__(256) void attn_k(const short* __restrict__ Q,
                                              const short* __restrict__ K,
                                              const short* __restrict__ Vt,
                                              short* __restrict__ AO) {
  __shared__ short Ks[32 * 72];  // 32 keys x 64 d, stride 72 (144B, 16B-mult)
  __shared__ short Vs[64 * 40];  // 64 d x 32 keys, stride 40 (80B, 16B-mult)
  const int tid = threadIdx.x;
  const int qt = blockIdx.x;
  const int bh = blockIdx.y;
  const int q0 = qt * 64;
  const int w = tid >> 6, lane = tid & 63;
  const int lr = lane & 15, lg = lane >> 4;
  const int qrow = q0 + w * 16 + lr;  // this lane's q column in S^T

  const size_t headQK = (size_t)bh * S_LEN * HDIM;
  const size_t headV = (size_t)bh * HDIM * S_LEN;

  s16x4 qf[4];
#pragma unroll
  for (int dc = 0; dc < 4; ++dc)
    qf[dc] = *(const s16x4*)&Q[headQK + (size_t)qrow * HDIM + dc * 16 + lg * 4];

  f32x4 o[4] = {};
  float m_run = -1e30f, l_run = 0.f;
  const float LOG2E = 1.4426950408889634f;

  const int ntile = qt * 2 + 2;
  for (int t = 0; t < ntile; ++t) {
    const int kv0 = t * 32;
    {  // stage K tile
      int rr = tid >> 3, cc = tid & 7;
      int4 v = *(const int4*)&K[headQK + (size_t)(kv0 + rr) * HDIM + cc * 8];
      *(int4*)&Ks[rr * 72 + cc * 8] = v;
    }
    {  // stage V^T tile
      int rr = tid >> 2, cc = tid & 3;
      int4 v = *(const int4*)&Vt[headV + (size_t)rr * S_LEN + kv0 + cc * 8];
      *(int4*)&Vs[rr * 40 + cc * 8] = v;
    }
    __syncthreads();

    // scores^T[key][q] over 32 keys (2 mfma k-steps)
    f32x4 sc[2];
#pragma unroll
    for (int ks = 0; ks < 2; ++ks) {
      f32x4 z = {0.f, 0.f, 0.f, 0.f};
      sc[ks] = z;
#pragma unroll
      for (int dc = 0; dc < 4; ++dc) {
        s16x4 kf = *(const s16x4*)&Ks[(ks * 16 + lr) * 72 + dc * 16 + lg * 4];
        sc[ks] = __builtin_amdgcn_mfma_f32_16x16x16bf16_1k(kf, qf[dc], sc[ks], 0, 0, 0);
      }
    }

    float p[2][4];
    float tm = -1e30f;
#pragma unroll
    for (int ks = 0; ks < 2; ++ks)
#pragma unroll
      for (int j = 0; j < 4; ++j) {
        int key = kv0 + ks * 16 + lg * 4 + j;
        float s = sc[ks][j] * 0.125f;
        if (key > qrow) s = -1e30f;
        p[ks][j] = s;
        tm = fmaxf(tm, s);
      }
    tm = fmaxf(tm, __shfl_xor(tm, 16));
    tm = fmaxf(tm, __shfl_xor(tm, 32));
    const float m_new = fmaxf(m_run, tm);
    const float corr = exp2f((m_run - m_new) * LOG2E);
    float psum = 0.f;
    s16x4 pf[2];
#pragma unroll
    for (int ks = 0; ks < 2; ++ks)
#pragma unroll
      for (int j = 0; j < 4; ++j) {
        float e = exp2f((p[ks][j] - m_new) * LOG2E);
        psum += e;
        pf[ks][j] = f2bf(e);
      }
    psum += __shfl_xor(psum, 16);
    psum += __shfl_xor(psum, 32);
    l_run = l_run * corr + psum;
    m_run = m_new;
#pragma unroll
    for (int dc = 0; dc < 4; ++dc) {
      o[dc][0] *= corr; o[dc][1] *= corr; o[dc][2] *= corr; o[dc][3] *= corr;
    }
#pragma unroll
    for (int ks = 0; ks < 2; ++ks)
#pragma unroll
      for (int dc = 0; dc < 4; ++dc) {
        s16x4 vf = *(const s16x4*)&Vs[(dc * 16 + lr) * 40 + ks * 16 + lg * 4];
        o[dc] = __builtin_amdgcn_mfma_f32_16x16x16bf16_1k(vf, pf[ks], o[dc], 0, 0, 0);
      }
    __syncthreads();
  }

  const int b = bh >> 4, h = bh & 15;
  const float inv = 1.f / l_run;
#pragma unroll
  for (int dc = 0; dc < 4; ++dc) {
    s16x4 pk;
#pragma unroll
    for (int j = 0; j < 4; ++j) pk[j] = f2bf(o[dc][j] * inv);
    *(s16x4*)&AO[((size_t)(b * S_LEN + qrow)) * D_MODEL + h * HDIM + dc * 16 + lg * 4] = pk;
  }
}

// ---------------------------------------------------------------------------
extern "C" void kernel_launch(void* const* d_in, const int* in_sizes, int n_in,
                              void* d_out, int out_size, void* d_ws, size_t ws_size,
                              hipStream_t stream) {
  const float* X  = (const float*)d_in[0];
  const float* Wq = (const float*)d_in[1];
  const float* bq = (const float*)d_in[2];
  const float* Wk = (const float*)d_in[3];
  const float* bk = (const float*)d_in[4];
  const float* Wv = (const float*)d_in[5];
  const float* bv = (const float*)d_in[6];
  const float* Wo = (const float*)d_in[7];
  const float* bo = (const float*)d_in[8];
  (void)in_sizes; (void)n_in; (void)out_size; (void)ws_size;

  char* ws = (char*)d_ws;
  const size_t WSZ = (size_t)D_MODEL * D_MODEL * sizeof(short);  // 2 MB
  const size_t QSZ = (size_t)M_TOT * D_MODEL * sizeof(short);    // 8 MB
  short* Wtq = (short*)(ws + 0 * WSZ);
  short* Wtk = (short*)(ws + 1 * WSZ);
  short* Wtv = (short*)(ws + 2 * WSZ);
  short* Wto = (short*)(ws + 3 * WSZ);
  short* Qb  = (short*)(ws + 4 * WSZ);
  short* Kb  = (short*)(ws + 4 * WSZ + QSZ);
  short* Vtb = (short*)(ws + 4 * WSZ + 2 * QSZ);
  short* AO  = (short*)(ws + 4 * WSZ + 3 * QSZ);

  dim3 tb(32, 8), tg(32, 32);
  wtrans_k<<<tg, tb, 0, stream>>>(Wq, Wtq);
  wtrans_k<<<tg, tb, 0, stream>>>(Wk, Wtk);
  wtrans_k<<<tg, tb, 0, stream>>>(Wv, Wtv);
  wtrans_k<<<tg, tb, 0, stream>>>(Wo, Wto);

  dim3 gg(32, 8);
  gemm_k<0, 0><<<gg, 256, 0, stream>>>(X, Wtq, bq, Qb);
  gemm_k<0, 0><<<gg, 256, 0, stream>>>(X, Wtk, bk, Kb);
  gemm_k<0, 1><<<gg, 256, 0, stream>>>(X, Wtv, bv, Vtb);

  attn_k<<<dim3(32, 32), 256, 0, stream>>>(Qb, Kb, Vtb, AO);

  gemm_k<1, 2><<<gg, 256, 0, stream>>>(AO, Wto, bo, (float*)d_out);
}

// Round 2
// 237.514 us; speedup vs baseline: 1.3633x; 1.3633x over previous
//
#include <hip/hip_runtime.h>
#include <hip/hip_bf16.h>

#define S_LEN 2048
#define D_MODEL 1024
#define NHEAD 16
#define HDIM 64
#define BATCH 2
#define M_TOT (BATCH * S_LEN)   // 4096
#define KVB 64

typedef __attribute__((ext_vector_type(4))) float f32x4;
typedef __attribute__((ext_vector_type(4))) short s16x4;
typedef __attribute__((ext_vector_type(8))) short s16x8;

__device__ inline short f2bf(float f) {
  unsigned u = __float_as_uint(f);
  return (short)((u + 0x7fffu + ((u >> 16) & 1u)) >> 16);
}

// ---------------------------------------------------------------------------
// Fused weight transpose + cast for all 4 weights: Wt[n][k] = (bf16) W[k][n]
// grid (32,32,4), block (32,8)
// ---------------------------------------------------------------------------
__global__ __launch_bounds__(256) void wtrans_k(const float* __restrict__ W0,
                                                const float* __restrict__ W1,
                                                const float* __restrict__ W2,
                                                const float* __restrict__ W3,
                                                short* __restrict__ T0,
                                                short* __restrict__ T1,
                                                short* __restrict__ T2,
                                                short* __restrict__ T3) {
  const int z = blockIdx.z;
  const float* W = z == 0 ? W0 : z == 1 ? W1 : z == 2 ? W2 : W3;
  short* Wt = z == 0 ? T0 : z == 1 ? T1 : z == 2 ? T2 : T3;
  __shared__ float tile[32][33];
  const int tx = threadIdx.x, ty = threadIdx.y;
  const int n0 = blockIdx.x * 32, k0 = blockIdx.y * 32;
#pragma unroll
  for (int j = 0; j < 4; ++j)
    tile[ty + j * 8][tx] = W[(size_t)(k0 + ty + j * 8) * D_MODEL + n0 + tx];
  __syncthreads();
#pragma unroll
  for (int j = 0; j < 4; ++j)
    Wt[(size_t)(n0 + ty + j * 8) * D_MODEL + k0 + tx] = f2bf(tile[tx][ty + j * 8]);
}

// ---------------------------------------------------------------------------
// GEMM core: acc[4][4] += A[128 rows @ m0][1024] * Bt[128 rows @ n0][1024]^T
// BK=32, mfma 16x16x32 bf16, double-buffered LDS (stride 40 shorts = 80B,
// 16B-aligned rows, conflict-free for b128 frag reads and staged writes).
// AMODE 0: A fp32 (fused cast), AMODE 1: A bf16.
// ---------------------------------------------------------------------------
#define LDST 40
#define LDSBUF (128 * LDST)

template <int AMODE>
__device__ inline void gemm_core(const void* __restrict__ Ap,
                                 const short* __restrict__ Bt,
                                 short* As_base, short* Bs_base,
                                 int m0, int n0, f32x4 (&acc)[4][4]) {
  const int tid = threadIdx.x;
  const int lane = tid & 63, w = tid >> 6;
  const int wm = w >> 1, wn = w & 1;
  const int lr = lane & 15, lg = lane >> 4;
  const int r = tid >> 1, c = tid & 1;

  float4 ap[4];
  int4 ai[2], bi[2];

  auto loadA = [&](int kk) {
    if (AMODE == 0) {
      const float* A = (const float*)Ap;
      const float4* s = (const float4*)(A + (size_t)(m0 + r) * D_MODEL + kk + c * 16);
#pragma unroll
      for (int j = 0; j < 4; ++j) ap[j] = s[j];
    } else {
      const short* A = (const short*)Ap;
      const int4* s = (const int4*)(A + (size_t)(m0 + r) * D_MODEL + kk + c * 16);
      ai[0] = s[0]; ai[1] = s[1];
    }
  };
  auto loadB = [&](int kk) {
    const int4* s = (const int4*)(Bt + (size_t)(n0 + r) * D_MODEL + kk + c * 16);
    bi[0] = s[0]; bi[1] = s[1];
  };
  auto writeA = [&](int buf) {
    short* As = As_base + buf * LDSBUF;
    if (AMODE == 0) {
      const float* f = (const float*)ap;
      short tmp[16];
#pragma unroll
      for (int j = 0; j < 16; ++j) tmp[j] = f2bf(f[j]);
      *(s16x8*)&As[r * LDST + c * 16] = *(const s16x8*)tmp;
      *(s16x8*)&As[r * LDST + c * 16 + 8] = *(const s16x8*)(tmp + 8);
    } else {
      *(int4*)&As[r * LDST + c * 16] = ai[0];
      *(int4*)&As[r * LDST + c * 16 + 8] = ai[1];
    }
  };
  auto writeB = [&](int buf) {
    short* Bs = Bs_base + buf * LDSBUF;
    *(int4*)&Bs[r * LDST + c * 16] = bi[0];
    *(int4*)&Bs[r * LDST + c * 16 + 8] = bi[1];
  };

  loadA(0); loadB(0);
  writeA(0); writeB(0);
  __syncthreads();
  int cur = 0;
  for (int k0 = 0; k0 < D_MODEL; k0 += 32) {
    const bool more = (k0 + 32) < D_MODEL;
    if (more) { loadA(k0 + 32); loadB(k0 + 32); }
    const short* As = As_base + cur * LDSBUF;
    const short* Bs = Bs_base + cur * LDSBUF;
    s16x8 af[4], bfr[4];
#pragma unroll
    for (int i = 0; i < 4; ++i) {
      af[i]  = *(const s16x8*)&As[(wm * 64 + i * 16 + lr) * LDST + lg * 8];
      bfr[i] = *(const s16x8*)&Bs[(wn * 64 + i * 16 + lr) * LDST + lg * 8];
    }
#pragma unroll
    for (int mi = 0; mi < 4; ++mi)
#pragma unroll
      for (int ni = 0; ni < 4; ++ni)
        acc[mi][ni] = __builtin_amdgcn_mfma_f32_16x16x32_bf16(
            af[mi], bfr[ni], acc[mi][ni], 0, 0, 0);
    if (more) { writeA(cur ^ 1); writeB(cur ^ 1); }
    __syncthreads();
    cur ^= 1;
  }
}

// ---------------------------------------------------------------------------
// Fused QKV projection: grid (32, 8, 3). z: 0=Q, 1=K (head-split [b,h,s,d]),
// 2=V (head-split transposed [b,h,d,s]).
// ---------------------------------------------------------------------------
__global__ __launch_bounds__(256) void gemm_qkv_k(
    const float* __restrict__ X, const short* __restrict__ Wtq,
    const short* __restrict__ Wtk, const short* __restrict__ Wtv,
    const float* __restrict__ bq, const float* __restrict__ bk,
    const float* __restrict__ bv, short* __restrict__ Qb,
    short* __restrict__ Kb, short* __restrict__ Vtb) {
  __shared__ short As[2 * LDSBUF];
  __shared__ short Bs[2 * LDSBUF];
  const int z = blockIdx.z;
  const short* Bt = z == 0 ? Wtq : z == 1 ? Wtk : Wtv;
  const float* bias = z == 0 ? bq : z == 1 ? bk : bv;
  short* Cp = z == 0 ? Qb : z == 1 ? Kb : Vtb;
  const int m0 = blockIdx.x * 128, n0 = blockIdx.y * 128;

  f32x4 acc[4][4] = {};
  gemm_core<0>(X, Bt, As, Bs, m0, n0, acc);

  const int tid = threadIdx.x, lane = tid & 63, w = tid >> 6;
  const int wm = w >> 1, wn = w & 1;
  const int lr = lane & 15, lg = lane >> 4;
#pragma unroll
  for (int ni = 0; ni < 4; ++ni) {
    const int n = n0 + wn * 64 + ni * 16 + lr;
    const float bn = bias[n];
    const int h = n >> 6, d = n & 63;
#pragma unroll
    for (int mi = 0; mi < 4; ++mi) {
      const int mb = m0 + wm * 64 + mi * 16 + lg * 4;
      f32x4 v = acc[mi][ni];
      if (z < 2) {
#pragma unroll
        for (int j = 0; j < 4; ++j) {
          int m = mb + j;
          int b = m >> 11, s = m & 2047;
          Cp[((size_t)((b * NHEAD + h) * S_LEN) + s) * HDIM + d] = f2bf(v[j] + bn);
        }
      } else {
        int b = mb >> 11, s = mb & 2047;
        s16x4 p;
#pragma unroll
        for (int j = 0; j < 4; ++j) p[j] = f2bf(v[j] + bn);
        *(s16x4*)&Cp[((size_t)((b * NHEAD + h) * HDIM) + d) * S_LEN + s] = p;
      }
    }
  }
}

// ---------------------------------------------------------------------------
// Output projection: bf16 A (attn output) -> fp32 out. grid (32, 8).
// ---------------------------------------------------------------------------
__global__ __launch_bounds__(256) void gemm_o_k(const short* __restrict__ A,
                                                const short* __restrict__ Bt,
                                                const float* __restrict__ bias,
                                                float* __restrict__ C) {
  __shared__ short As[2 * LDSBUF];
  __shared__ short Bs[2 * LDSBUF];
  const int m0 = blockIdx.x * 128, n0 = blockIdx.y * 128;
  f32x4 acc[4][4] = {};
  gemm_core<1>(A, Bt, As, Bs, m0, n0, acc);

  const int tid = threadIdx.x, lane = tid & 63, w = tid >> 6;
  const int wm = w >> 1, wn = w & 1;
  const int lr = lane & 15, lg = lane >> 4;
#pragma unroll
  for (int ni = 0; ni < 4; ++ni) {
    const int n = n0 + wn * 64 + ni * 16 + lr;
    const float bn = bias[n];
#pragma unroll
    for (int mi = 0; mi < 4; ++mi) {
      const int mb = m0 + wm * 64 + mi * 16 + lg * 4;
      f32x4 v = acc[mi][ni];
#pragma unroll
      for (int j = 0; j < 4; ++j)
        C[(size_t)(mb + j) * D_MODEL + n] = v[j] + bn;
    }
  }
}

// ---------------------------------------------------------------------------
// Flash attention (causal). grid (16 pairs, 32 bh), block 256 (4 waves).
// Each block handles q-tiles {31-pi, pi} (64 rows each) -> exactly 33
// 64-key kv-tiles of work per block (perfect balance).
// Double-buffered K/V staging with register prefetch.
// QK^T via mfma 16x16x32 (swapped operands: S^T = K @ Q^T), PV via 16x16x16.
// Q,K: [bh][2048][64] bf16; Vt: [bh][64][2048] bf16; AO: [4096][1024] bf16.
// ---------------------------------------------------------------------------
__global__ __launch_bounds__(256) void attn_k(const short* __restrict__ Q,
                                              const short* __restrict__ K,
                                              const short* __restrict__ Vt,
                                              short* __restrict__ AO) {
  __shared__ short Ks[2 * KVB * 72];
  __shared__ short Vs[2 * KVB * 72];
  const int tid = threadIdx.x, w = tid >> 6, lane = tid & 63;
  const int lr = lane & 15, lg = lane >> 4;
  const int bh = blockIdx.y, b = bh >> 4, h = bh & 15;
  const size_t headQK = (size_t)bh * S_LEN * HDIM;
  const size_t headV = (size_t)bh * HDIM * S_LEN;
  const int rS = tid >> 2, cS = (tid & 3) * 16;  // staging coords

  int4 kpre[2], vpre[2];
  auto loadKV = [&](int kv0) {
    const int4* ks = (const int4*)&K[headQK + (size_t)(kv0 + rS) * HDIM + cS];
    kpre[0] = ks[0]; kpre[1] = ks[1];
    const int4* vs = (const int4*)&Vt[headV + (size_t)rS * S_LEN + kv0 + cS];
    vpre[0] = vs[0]; vpre[1] = vs[1];
  };
  auto writeKV = [&](int buf) {
    *(int4*)&Ks[buf * (KVB * 72) + rS * 72 + cS] = kpre[0];
    *(int4*)&Ks[buf * (KVB * 72) + rS * 72 + cS + 8] = kpre[1];
    *(int4*)&Vs[buf * (KVB * 72) + rS * 72 + cS] = vpre[0];
    *(int4*)&Vs[buf * (KVB * 72) + rS * 72 + cS + 8] = vpre[1];
  };

  const float SC2 = 0.18033688011112042f;  // (1/8) * log2(e)

  for (int hv = 0; hv < 2; ++hv) {
    const int qt = hv ? (int)blockIdx.x : 31 - (int)blockIdx.x;
    const int q0 = qt * 64, nt = qt + 1;
    const int qrow = q0 + w * 16 + lr;

    const s16x8 qf0 = *(const s16x8*)&Q[headQK + (size_t)qrow * HDIM + lg * 8];
    const s16x8 qf1 = *(const s16x8*)&Q[headQK + (size_t)qrow * HDIM + 32 + lg * 8];

    f32x4 o[4] = {};
    float m_run = -1e30f, l_run = 0.f;

    loadKV(0);
    writeKV(0);
    __syncthreads();

    for (int t = 0; t < nt; ++t) {
      if (t + 1 < nt) loadKV((t + 1) * KVB);
      const short* Kc = &Ks[(t & 1) * (KVB * 72)];
      const short* Vc = &Vs[(t & 1) * (KVB * 72)];

      // scores^T: 4 groups of 16 keys, 2 mfma (d=0..31, 32..63) each
      f32x4 sc[4];
#pragma unroll
      for (int g = 0; g < 4; ++g) {
        const s16x8 kf0 = *(const s16x8*)&Kc[(g * 16 + lr) * 72 + lg * 8];
        const s16x8 kf1 = *(const s16x8*)&Kc[(g * 16 + lr) * 72 + 32 + lg * 8];
        f32x4 z = {0.f, 0.f, 0.f, 0.f};
        sc[g] = __builtin_amdgcn_mfma_f32_16x16x32_bf16(kf0, qf0, z, 0, 0, 0);
        sc[g] = __builtin_amdgcn_mfma_f32_16x16x32_bf16(kf1, qf1, sc[g], 0, 0, 0);
      }

      // online softmax in log2 domain
      const int kv0 = t * KVB;
      const bool diag = (t == nt - 1);
      float p2[4][4];
      float tm = -1e30f;
#pragma unroll
      for (int g = 0; g < 4; ++g)
#pragma unroll
        for (int j = 0; j < 4; ++j) {
          float s2 = sc[g][j] * SC2;
          if (diag && (kv0 + g * 16 + lg * 4 + j) > qrow) s2 = -1e30f;
          p2[g][j] = s2;
          tm = fmaxf(tm, s2);
        }
      tm = fmaxf(tm, __shfl_xor(tm, 16));
      tm = fmaxf(tm, __shfl_xor(tm, 32));
      const float mnew = fmaxf(m_run, tm);
      const float corr = exp2f(m_run - mnew);
      float ps = 0.f;
      s16x4 pf[4];
#pragma unroll
      for (int g = 0; g < 4; ++g)
#pragma unroll
        for (int j = 0; j < 4; ++j) {
          float e = exp2f(p2[g][j] - mnew);
          ps += e;
          pf[g][j] = f2bf(e);
        }
      ps += __shfl_xor(ps, 16);
      ps += __shfl_xor(ps, 32);
      l_run = l_run * corr + ps;
      m_run = mnew;
#pragma unroll
      for (int dc = 0; dc < 4; ++dc) o[dc] = o[dc] * corr;

#pragma unroll
      for (int g = 0; g < 4; ++g)
#pragma unroll
        for (int dc = 0; dc < 4; ++dc) {
          const s16x4 vf = *(const s16x4*)&Vc[(dc * 16 + lr) * 72 + g * 16 + lg * 4];
          o[dc] = __builtin_amdgcn_mfma_f32_16x16x16bf16_1k(vf, pf[g], o[dc], 0, 0, 0);
        }

      if (t + 1 < nt) writeKV((t + 1) & 1);
      __syncthreads();
    }

    const float inv = 1.f / l_run;
#pragma unroll
    for (int dc = 0; dc < 4; ++dc) {
      s16x4 pk;
#pragma unroll
      for (int j = 0; j < 4; ++j) pk[j] = f2bf(o[dc][j] * inv);
      *(s16x4*)&AO[((size_t)(b * S_LEN + qrow)) * D_MODEL + h * HDIM + dc * 16 + lg * 4] = pk;
    }
  }
}

// ---------------------------------------------------------------------------
extern "C" void kernel_launch(void* const* d_in, const int* in_sizes, int n_in,
                              void* d_out, int out_size, void* d_ws, size_t ws_size,
                              hipStream_t stream) {
  const float* X  = (const float*)d_in[0];
  const float* Wq = (const float*)d_in[1];
  const float* bq = (const float*)d_in[2];
  const float* Wk = (const float*)d_in[3];
  const float* bk = (const float*)d_in[4];
  const float* Wv = (const float*)d_in[5];
  const float* bv = (const float*)d_in[6];
  const float* Wo = (const float*)d_in[7];
  const float* bo = (const float*)d_in[8];
  (void)in_sizes; (void)n_in; (void)out_size; (void)ws_size;

  char* ws = (char*)d_ws;
  const size_t WSZ = (size_t)D_MODEL * D_MODEL * sizeof(short);  // 2 MB
  const size_t QSZ = (size_t)M_TOT * D_MODEL * sizeof(short);    // 8 MB
  short* Wtq = (short*)(ws + 0 * WSZ);
  short* Wtk = (short*)(ws + 1 * WSZ);
  short* Wtv = (short*)(ws + 2 * WSZ);
  short* Wto = (short*)(ws + 3 * WSZ);
  short* Qb  = (short*)(ws + 4 * WSZ);
  short* Kb  = (short*)(ws + 4 * WSZ + QSZ);
  short* Vtb = (short*)(ws + 4 * WSZ + 2 * QSZ);
  short* AO  = (short*)(ws + 4 * WSZ + 3 * QSZ);

  wtrans_k<<<dim3(32, 32, 4), dim3(32, 8), 0, stream>>>(Wq, Wk, Wv, Wo,
                                                        Wtq, Wtk, Wtv, Wto);

  gemm_qkv_k<<<dim3(32, 8, 3), 256, 0, stream>>>(X, Wtq, Wtk, Wtv, bq, bk, bv,
                                                 Qb, Kb, Vtb);

  attn_k<<<dim3(16, 32), 256, 0, stream>>>(Qb, Kb, Vtb, AO);

  gemm_o_k<<<dim3(32, 8), 256, 0, stream>>>(AO, Wto, bo, (float*)d_out);
}

// Round 3
// 172.320 us; speedup vs baseline: 1.8790x; 1.3783x over previous
//
#include <hip/hip_runtime.h>
#include <hip/hip_bf16.h>

#define S_LEN 2048
#define D_MODEL 1024
#define NHEAD 16
#define HDIM 64
#define BATCH 2
#define M_TOT (BATCH * S_LEN)   // 4096
#define KVB 64

typedef __attribute__((ext_vector_type(4))) float f32x4;
typedef __attribute__((ext_vector_type(4))) short s16x4;
typedef __attribute__((ext_vector_type(8))) short s16x8;

#define AS1 __attribute__((address_space(1)))
#define AS3 __attribute__((address_space(3)))

__device__ inline short f2bf(float f) {
  unsigned u = __float_as_uint(f);
  return (short)((u + 0x7fffu + ((u >> 16) & 1u)) >> 16);
}

__device__ __forceinline__ void gl_lds16(const short* g, short* l) {
  __builtin_amdgcn_global_load_lds((const AS1 void*)g, (AS3 void*)l, 16, 0, 0);
}

// ---------------------------------------------------------------------------
// X fp32 -> bf16 cast. grid 2048, block 256, 8 elems/thread.
// ---------------------------------------------------------------------------
__global__ __launch_bounds__(256) void xcast_k(const float* __restrict__ X,
                                               short* __restrict__ Xb) {
  const size_t i = ((size_t)blockIdx.x * 256 + threadIdx.x) * 8;
  float4 a = *(const float4*)&X[i];
  float4 b = *(const float4*)&X[i + 4];
  s16x8 p;
  p[0] = f2bf(a.x); p[1] = f2bf(a.y); p[2] = f2bf(a.z); p[3] = f2bf(a.w);
  p[4] = f2bf(b.x); p[5] = f2bf(b.y); p[6] = f2bf(b.z); p[7] = f2bf(b.w);
  *(s16x8*)&Xb[i] = p;
}

// ---------------------------------------------------------------------------
// Weight transpose + cast, all 4 weights into contiguous Wcat[z][n][k].
// grid (32,32,4), block (32,8)
// ---------------------------------------------------------------------------
__global__ __launch_bounds__(256) void wtrans_k(const float* __restrict__ W0,
                                                const float* __restrict__ W1,
                                                const float* __restrict__ W2,
                                                const float* __restrict__ W3,
                                                short* __restrict__ Wcat) {
  const int z = blockIdx.z;
  const float* W = z == 0 ? W0 : z == 1 ? W1 : z == 2 ? W2 : W3;
  short* Wt = Wcat + (size_t)z * D_MODEL * D_MODEL;
  __shared__ float tile[32][33];
  const int tx = threadIdx.x, ty = threadIdx.y;
  const int n0 = blockIdx.x * 32, k0 = blockIdx.y * 32;
#pragma unroll
  for (int j = 0; j < 4; ++j)
    tile[ty + j * 8][tx] = W[(size_t)(k0 + ty + j * 8) * D_MODEL + n0 + tx];
  __syncthreads();
#pragma unroll
  for (int j = 0; j < 4; ++j)
    Wt[(size_t)(n0 + ty + j * 8) * D_MODEL + k0 + tx] = f2bf(tile[tx][ty + j * 8]);
}

// ---------------------------------------------------------------------------
// GEMM core (m97 structure): 128x128 tile, BK=64, mfma 16x16x32 bf16.
// Staging via global_load_lds width-16 into LINEAR LDS [128][64] shorts
// (row stride 128B). XOR slot-swizzle (slot ^= row&7, 16B granule) applied
// as inverse-permuted GLOBAL source + same permutation on ds_read -> all 32
// banks covered by 8 consecutive rows, conflict-free b128 fragment reads.
// Single-buffered, 2 barriers per k-step. A, Bt both bf16 row-major [.,K=1024].
// ---------------------------------------------------------------------------
__device__ __forceinline__ void gemm_core_bf16(const short* __restrict__ A,
                                               const short* __restrict__ Bt,
                                               short* As, short* Bs,
                                               int m0, int n0,
                                               f32x4 (&acc)[4][4]) {
  const int tid = threadIdx.x;
  const int lane = tid & 63, w = tid >> 6;
  const int wm = w >> 1, wn = w & 1;
  const int lr = lane & 15, lg = lane >> 4;
  const int lr8 = lane >> 3;          // row within 8-row group
  const int sl = lane & 7;            // linear 16B slot
  const int scol = ((sl ^ lr8) << 3); // inverse-swizzled source col (shorts)

  for (int k0 = 0; k0 < D_MODEL; k0 += 64) {
    // ---- stage: 4 issues/wave for A, 4 for B (each issue = 8 rows x 128B)
#pragma unroll
    for (int j = 0; j < 4; ++j) {
      const int rb = j * 4 + w;       // 8-row group 0..15
      const int row = rb * 8 + lr8;
      gl_lds16(&A[(size_t)(m0 + row) * D_MODEL + k0 + scol], &As[rb * 512]);
      gl_lds16(&Bt[(size_t)(n0 + row) * D_MODEL + k0 + scol], &Bs[rb * 512]);
    }
    __syncthreads();   // (compiler emits vmcnt(0) drain before barrier)

#pragma unroll
    for (int ks = 0; ks < 2; ++ks) {
      s16x8 af[4], bfr[4];
#pragma unroll
      for (int i = 0; i < 4; ++i) {
        const int Ra = wm * 64 + i * 16 + lr;
        const int Rb = wn * 64 + i * 16 + lr;
        af[i]  = *(const s16x8*)&As[Ra * 64 + ((((ks << 2) | lg) ^ (Ra & 7)) << 3)];
        bfr[i] = *(const s16x8*)&Bs[Rb * 64 + ((((ks << 2) | lg) ^ (Rb & 7)) << 3)];
      }
#pragma unroll
      for (int mi = 0; mi < 4; ++mi)
#pragma unroll
        for (int ni = 0; ni < 4; ++ni)
          acc[mi][ni] = __builtin_amdgcn_mfma_f32_16x16x32_bf16(
              af[mi], bfr[ni], acc[mi][ni], 0, 0, 0);
    }
    __syncthreads();
  }
}

// ---------------------------------------------------------------------------
// Fused QKV projection: one GEMM, N = 3072 (Wq|Wk|Wv rows concatenated).
// grid flat (32 x 24) with XCD-bijective swizzle. z = n0>>10 routes output:
// z<2 -> head-split [b,h,s,d]; z==2 -> V transposed [b,h,d,s].
// ---------------------------------------------------------------------------
__global__ __launch_bounds__(256) void gemm_qkv_k(
    const short* __restrict__ Xb, const short* __restrict__ Wcat,
    const float* __restrict__ bq, const float* __restrict__ bk,
    const float* __restrict__ bv, short* __restrict__ Qb,
    short* __restrict__ Kb, short* __restrict__ Vtb) {
  __shared__ short As[128 * 64];
  __shared__ short Bs[128 * 64];
  const int nwg = gridDim.x * gridDim.y;           // 768, %8==0
  const int orig = blockIdx.y * gridDim.x + blockIdx.x;
  const int wg = (orig & 7) * (nwg >> 3) + (orig >> 3);
  const int m0 = (wg & 31) * 128;                  // gridDim.x == 32
  const int n0 = (wg >> 5) * 128;

  f32x4 acc[4][4] = {};
  gemm_core_bf16(Xb, Wcat, As, Bs, m0, n0, acc);

  const int z = n0 >> 10;
  const float* bias = z == 0 ? bq : z == 1 ? bk : bv;
  short* Cp = z == 0 ? Qb : z == 1 ? Kb : Vtb;

  const int tid = threadIdx.x, lane = tid & 63, w = tid >> 6;
  const int wm = w >> 1, wn = w & 1;
  const int lr = lane & 15, lg = lane >> 4;
#pragma unroll
  for (int ni = 0; ni < 4; ++ni) {
    const int n = n0 + wn * 64 + ni * 16 + lr;
    const float bn = bias[n & 1023];
    const int h = (n >> 6) & 15, d = n & 63;
#pragma unroll
    for (int mi = 0; mi < 4; ++mi) {
      const int mb = m0 + wm * 64 + mi * 16 + lg * 4;
      f32x4 v = acc[mi][ni];
      if (z < 2) {
#pragma unroll
        for (int j = 0; j < 4; ++j) {
          int m = mb + j;
          int b = m >> 11, s = m & 2047;
          Cp[((size_t)((b * NHEAD + h) * S_LEN) + s) * HDIM + d] = f2bf(v[j] + bn);
        }
      } else {
        int b = mb >> 11, s = mb & 2047;
        s16x4 p;
#pragma unroll
        for (int j = 0; j < 4; ++j) p[j] = f2bf(v[j] + bn);
        *(s16x4*)&Cp[((size_t)((b * NHEAD + h) * HDIM) + d) * S_LEN + s] = p;
      }
    }
  }
}

// ---------------------------------------------------------------------------
// Output projection: bf16 A (attn out) @ Wto^T + bo -> fp32. grid flat 32x8.
// ---------------------------------------------------------------------------
__global__ __launch_bounds__(256) void gemm_o_k(const short* __restrict__ A,
                                                const short* __restrict__ Bt,
                                                const float* __restrict__ bias,
                                                float* __restrict__ C) {
  __shared__ short As[128 * 64];
  __shared__ short Bs[128 * 64];
  const int nwg = gridDim.x * gridDim.y;           // 256
  const int orig = blockIdx.y * gridDim.x + blockIdx.x;
  const int wg = (orig & 7) * (nwg >> 3) + (orig >> 3);
  const int m0 = (wg & 31) * 128;
  const int n0 = (wg >> 5) * 128;

  f32x4 acc[4][4] = {};
  gemm_core_bf16(A, Bt, As, Bs, m0, n0, acc);

  const int tid = threadIdx.x, lane = tid & 63, w = tid >> 6;
  const int wm = w >> 1, wn = w & 1;
  const int lr = lane & 15, lg = lane >> 4;
#pragma unroll
  for (int ni = 0; ni < 4; ++ni) {
    const int n = n0 + wn * 64 + ni * 16 + lr;
    const float bn = bias[n];
#pragma unroll
    for (int mi = 0; mi < 4; ++mi) {
      const int mb = m0 + wm * 64 + mi * 16 + lg * 4;
      f32x4 v = acc[mi][ni];
#pragma unroll
      for (int j = 0; j < 4; ++j)
        C[(size_t)(mb + j) * D_MODEL + n] = v[j] + bn;
    }
  }
}

// ---------------------------------------------------------------------------
// Flash attention (causal). grid (16 pairs, 32 bh), block 256 (4 waves).
// Each block handles q-tiles {31-pi, pi} -> exactly 33 kv-tiles (balanced).
// Double-buffered K/V staging with register prefetch.
// QK^T via mfma 16x16x32 (S^T = K @ Q^T), PV via 16x16x16.
// ---------------------------------------------------------------------------
__global__ __launch_bounds__(256) void attn_k(const short* __restrict__ Q,
                                              const short* __restrict__ K,
                                              const short* __restrict__ Vt,
                                              short* __restrict__ AO) {
  __shared__ short Ks[2 * KVB * 72];
  __shared__ short Vs[2 * KVB * 72];
  const int tid = threadIdx.x, w = tid >> 6, lane = tid & 63;
  const int lr = lane & 15, lg = lane >> 4;
  const int bh = blockIdx.y, b = bh >> 4, h = bh & 15;
  const size_t headQK = (size_t)bh * S_LEN * HDIM;
  const size_t headV = (size_t)bh * HDIM * S_LEN;
  const int rS = tid >> 2, cS = (tid & 3) * 16;

  int4 kpre[2], vpre[2];
  auto loadKV = [&](int kv0) {
    const int4* ks = (const int4*)&K[headQK + (size_t)(kv0 + rS) * HDIM + cS];
    kpre[0] = ks[0]; kpre[1] = ks[1];
    const int4* vs = (const int4*)&Vt[headV + (size_t)rS * S_LEN + kv0 + cS];
    vpre[0] = vs[0]; vpre[1] = vs[1];
  };
  auto writeKV = [&](int buf) {
    *(int4*)&Ks[buf * (KVB * 72) + rS * 72 + cS] = kpre[0];
    *(int4*)&Ks[buf * (KVB * 72) + rS * 72 + cS + 8] = kpre[1];
    *(int4*)&Vs[buf * (KVB * 72) + rS * 72 + cS] = vpre[0];
    *(int4*)&Vs[buf * (KVB * 72) + rS * 72 + cS + 8] = vpre[1];
  };

  const float SC2 = 0.18033688011112042f;  // (1/8) * log2(e)

  for (int hv = 0; hv < 2; ++hv) {
    const int qt = hv ? (int)blockIdx.x : 31 - (int)blockIdx.x;
    const int q0 = qt * 64, nt = qt + 1;
    const int qrow = q0 + w * 16 + lr;

    const s16x8 qf0 = *(const s16x8*)&Q[headQK + (size_t)qrow * HDIM + lg * 8];
    const s16x8 qf1 = *(const s16x8*)&Q[headQK + (size_t)qrow * HDIM + 32 + lg * 8];

    f32x4 o[4] = {};
    float m_run = -1e30f, l_run = 0.f;

    loadKV(0);
    writeKV(0);
    __syncthreads();

    for (int t = 0; t < nt; ++t) {
      if (t + 1 < nt) loadKV((t + 1) * KVB);
      const short* Kc = &Ks[(t & 1) * (KVB * 72)];
      const short* Vc = &Vs[(t & 1) * (KVB * 72)];

      f32x4 sc[4];
#pragma unroll
      for (int g = 0; g < 4; ++g) {
        const s16x8 kf0 = *(const s16x8*)&Kc[(g * 16 + lr) * 72 + lg * 8];
        const s16x8 kf1 = *(const s16x8*)&Kc[(g * 16 + lr) * 72 + 32 + lg * 8];
        f32x4 z = {0.f, 0.f, 0.f, 0.f};
        sc[g] = __builtin_amdgcn_mfma_f32_16x16x32_bf16(kf0, qf0, z, 0, 0, 0);
        sc[g] = __builtin_amdgcn_mfma_f32_16x16x32_bf16(kf1, qf1, sc[g], 0, 0, 0);
      }

      const int kv0 = t * KVB;
      const bool diag = (t == nt - 1);
      float p2[4][4];
      float tm = -1e30f;
#pragma unroll
      for (int g = 0; g < 4; ++g)
#pragma unroll
        for (int j = 0; j < 4; ++j) {
          float s2 = sc[g][j] * SC2;
          if (diag && (kv0 + g * 16 + lg * 4 + j) > qrow) s2 = -1e30f;
          p2[g][j] = s2;
          tm = fmaxf(tm, s2);
        }
      tm = fmaxf(tm, __shfl_xor(tm, 16));
      tm = fmaxf(tm, __shfl_xor(tm, 32));
      const float mnew = fmaxf(m_run, tm);
      const float corr = exp2f(m_run - mnew);
      float ps = 0.f;
      s16x4 pf[4];
#pragma unroll
      for (int g = 0; g < 4; ++g)
#pragma unroll
        for (int j = 0; j < 4; ++j) {
          float e = exp2f(p2[g][j] - mnew);
          ps += e;
          pf[g][j] = f2bf(e);
        }
      ps += __shfl_xor(ps, 16);
      ps += __shfl_xor(ps, 32);
      l_run = l_run * corr + ps;
      m_run = mnew;
#pragma unroll
      for (int dc = 0; dc < 4; ++dc) o[dc] = o[dc] * corr;

#pragma unroll
      for (int g = 0; g < 4; ++g)
#pragma unroll
        for (int dc = 0; dc < 4; ++dc) {
          const s16x4 vf = *(const s16x4*)&Vc[(dc * 16 + lr) * 72 + g * 16 + lg * 4];
          o[dc] = __builtin_amdgcn_mfma_f32_16x16x16bf16_1k(vf, pf[g], o[dc], 0, 0, 0);
        }

      if (t + 1 < nt) writeKV((t + 1) & 1);
      __syncthreads();
    }

    const float inv = 1.f / l_run;
#pragma unroll
    for (int dc = 0; dc < 4; ++dc) {
      s16x4 pk;
#pragma unroll
      for (int j = 0; j < 4; ++j) pk[j] = f2bf(o[dc][j] * inv);
      *(s16x4*)&AO[((size_t)(b * S_LEN + qrow)) * D_MODEL + h * HDIM + dc * 16 + lg * 4] = pk;
    }
  }
}

// ---------------------------------------------------------------------------
extern "C" void kernel_launch(void* const* d_in, const int* in_sizes, int n_in,
                              void* d_out, int out_size, void* d_ws, size_t ws_size,
                              hipStream_t stream) {
  const float* X  = (const float*)d_in[0];
  const float* Wq = (const float*)d_in[1];
  const float* bq = (const float*)d_in[2];
  const float* Wk = (const float*)d_in[3];
  const float* bk = (const float*)d_in[4];
  const float* Wv = (const float*)d_in[5];
  const float* bv = (const float*)d_in[6];
  const float* Wo = (const float*)d_in[7];
  const float* bo = (const float*)d_in[8];
  (void)in_sizes; (void)n_in; (void)out_size; (void)ws_size;

  char* ws = (char*)d_ws;
  const size_t WSZ = (size_t)D_MODEL * D_MODEL * sizeof(short);  // 2 MB
  const size_t QSZ = (size_t)M_TOT * D_MODEL * sizeof(short);    // 8 MB
  short* Wcat = (short*)ws;                       // 4 matrices, 8 MB
  short* Qb  = (short*)(ws + 4 * WSZ);
  short* Kb  = (short*)(ws + 4 * WSZ + QSZ);
  short* Vtb = (short*)(ws + 4 * WSZ + 2 * QSZ);
  short* AO  = (short*)(ws + 4 * WSZ + 3 * QSZ);  // doubles as Xb (bf16 X)
  short* Xb  = AO;  // X-cast consumed before attn writes AO
  short* Wto = Wcat + 3 * (size_t)D_MODEL * D_MODEL;

  xcast_k<<<dim3(M_TOT * D_MODEL / 2048), 256, 0, stream>>>(X, Xb);
  wtrans_k<<<dim3(32, 32, 4), dim3(32, 8), 0, stream>>>(Wq, Wk, Wv, Wo, Wcat);

  gemm_qkv_k<<<dim3(32, 24), 256, 0, stream>>>(Xb, Wcat, bq, bk, bv,
                                               Qb, Kb, Vtb);

  attn_k<<<dim3(16, 32), 256, 0, stream>>>(Qb, Kb, Vtb, AO);

  gemm_o_k<<<dim3(32, 8), 256, 0, stream>>>(AO, Wto, bo, (float*)d_out);
}

// Round 4
// 135.762 us; speedup vs baseline: 2.3850x; 1.2693x over previous
//
#include <hip/hip_runtime.h>
#include <hip/hip_bf16.h>

#define S_LEN 2048
#define D_MODEL 1024
#define NHEAD 16
#define HDIM 64
#define BATCH 2
#define M_TOT (BATCH * S_LEN)   // 4096
#define KVB 64

typedef __attribute__((ext_vector_type(4))) float f32x4;
typedef __attribute__((ext_vector_type(4))) short s16x4;
typedef __attribute__((ext_vector_type(8))) short s16x8;

#define AS1 __attribute__((address_space(1)))
#define AS3 __attribute__((address_space(3)))

#define SC2 0.18033688011112042f  // (1/8) * log2(e)

__device__ inline short f2bf(float f) {
  unsigned u = __float_as_uint(f);
  return (short)((u + 0x7fffu + ((u >> 16) & 1u)) >> 16);
}

__device__ __forceinline__ void gl_lds16(const short* g, short* l) {
  __builtin_amdgcn_global_load_lds((const AS1 void*)g, (AS3 void*)l, 16, 0, 0);
}

// ---------------------------------------------------------------------------
// X fp32 -> bf16 cast. grid 2048, block 256, 8 elems/thread.
// ---------------------------------------------------------------------------
__global__ __launch_bounds__(256) void xcast_k(const float* __restrict__ X,
                                               short* __restrict__ Xb) {
  const size_t i = ((size_t)blockIdx.x * 256 + threadIdx.x) * 8;
  float4 a = *(const float4*)&X[i];
  float4 b = *(const float4*)&X[i + 4];
  s16x8 p;
  p[0] = f2bf(a.x); p[1] = f2bf(a.y); p[2] = f2bf(a.z); p[3] = f2bf(a.w);
  p[4] = f2bf(b.x); p[5] = f2bf(b.y); p[6] = f2bf(b.z); p[7] = f2bf(b.w);
  *(s16x8*)&Xb[i] = p;
}

// ---------------------------------------------------------------------------
// Weight transpose + cast, all 4 weights into contiguous Wcat[z][n][k].
// Wq (z==0) is pre-scaled by (1/8)*log2(e) so attention scores come out of
// QK^T already in the log2 softmax domain (kills 16 muls/tile/lane in attn).
// grid (32,32,4), block (32,8)
// ---------------------------------------------------------------------------
__global__ __launch_bounds__(256) void wtrans_k(const float* __restrict__ W0,
                                                const float* __restrict__ W1,
                                                const float* __restrict__ W2,
                                                const float* __restrict__ W3,
                                                short* __restrict__ Wcat) {
  const int z = blockIdx.z;
  const float* W = z == 0 ? W0 : z == 1 ? W1 : z == 2 ? W2 : W3;
  short* Wt = Wcat + (size_t)z * D_MODEL * D_MODEL;
  const float scl = (z == 0) ? SC2 : 1.f;
  __shared__ float tile[32][33];
  const int tx = threadIdx.x, ty = threadIdx.y;
  const int n0 = blockIdx.x * 32, k0 = blockIdx.y * 32;
#pragma unroll
  for (int j = 0; j < 4; ++j)
    tile[ty + j * 8][tx] = W[(size_t)(k0 + ty + j * 8) * D_MODEL + n0 + tx];
  __syncthreads();
#pragma unroll
  for (int j = 0; j < 4; ++j)
    Wt[(size_t)(n0 + ty + j * 8) * D_MODEL + k0 + tx] =
        f2bf(tile[tx][ty + j * 8] * scl);
}

// ---------------------------------------------------------------------------
// GEMM core (m97 structure): 128x128 tile, BK=64, mfma 16x16x32 bf16.
// global_load_lds width-16 into LINEAR LDS [128][64] shorts; XOR slot-swizzle
// (slot ^= row&7) as inverse-permuted GLOBAL source + same perm on ds_read.
// ---------------------------------------------------------------------------
__device__ __forceinline__ void gemm_core_bf16(const short* __restrict__ A,
                                               const short* __restrict__ Bt,
                                               short* As, short* Bs,
                                               int m0, int n0,
                                               f32x4 (&acc)[4][4]) {
  const int tid = threadIdx.x;
  const int lane = tid & 63, w = tid >> 6;
  const int wm = w >> 1, wn = w & 1;
  const int lr = lane & 15, lg = lane >> 4;
  const int lr8 = lane >> 3;
  const int sl = lane & 7;
  const int scol = ((sl ^ lr8) << 3);

  for (int k0 = 0; k0 < D_MODEL; k0 += 64) {
#pragma unroll
    for (int j = 0; j < 4; ++j) {
      const int rb = j * 4 + w;
      const int row = rb * 8 + lr8;
      gl_lds16(&A[(size_t)(m0 + row) * D_MODEL + k0 + scol], &As[rb * 512]);
      gl_lds16(&Bt[(size_t)(n0 + row) * D_MODEL + k0 + scol], &Bs[rb * 512]);
    }
    __syncthreads();

#pragma unroll
    for (int ks = 0; ks < 2; ++ks) {
      s16x8 af[4], bfr[4];
#pragma unroll
      for (int i = 0; i < 4; ++i) {
        const int Ra = wm * 64 + i * 16 + lr;
        const int Rb = wn * 64 + i * 16 + lr;
        af[i]  = *(const s16x8*)&As[Ra * 64 + ((((ks << 2) | lg) ^ (Ra & 7)) << 3)];
        bfr[i] = *(const s16x8*)&Bs[Rb * 64 + ((((ks << 2) | lg) ^ (Rb & 7)) << 3)];
      }
#pragma unroll
      for (int mi = 0; mi < 4; ++mi)
#pragma unroll
        for (int ni = 0; ni < 4; ++ni)
          acc[mi][ni] = __builtin_amdgcn_mfma_f32_16x16x32_bf16(
              af[mi], bfr[ni], acc[mi][ni], 0, 0, 0);
    }
    __syncthreads();
  }
}

// ---------------------------------------------------------------------------
// Fused QKV projection: one GEMM, N = 3072 (Wq|Wk|Wv rows concatenated).
// grid flat (32 x 24) with XCD-bijective swizzle. z = n0>>10 routes output.
// ---------------------------------------------------------------------------
__global__ __launch_bounds__(256) void gemm_qkv_k(
    const short* __restrict__ Xb, const short* __restrict__ Wcat,
    const float* __restrict__ bq, const float* __restrict__ bk,
    const float* __restrict__ bv, short* __restrict__ Qb,
    short* __restrict__ Kb, short* __restrict__ Vtb) {
  __shared__ short As[128 * 64];
  __shared__ short Bs[128 * 64];
  const int nwg = gridDim.x * gridDim.y;           // 768, %8==0
  const int orig = blockIdx.y * gridDim.x + blockIdx.x;
  const int wg = (orig & 7) * (nwg >> 3) + (orig >> 3);
  const int m0 = (wg & 31) * 128;
  const int n0 = (wg >> 5) * 128;

  f32x4 acc[4][4] = {};
  gemm_core_bf16(Xb, Wcat, As, Bs, m0, n0, acc);

  const int z = n0 >> 10;
  const float* bias = z == 0 ? bq : z == 1 ? bk : bv;
  short* Cp = z == 0 ? Qb : z == 1 ? Kb : Vtb;
  const float bscl = (z == 0) ? SC2 : 1.f;

  const int tid = threadIdx.x, lane = tid & 63, w = tid >> 6;
  const int wm = w >> 1, wn = w & 1;
  const int lr = lane & 15, lg = lane >> 4;
#pragma unroll
  for (int ni = 0; ni < 4; ++ni) {
    const int n = n0 + wn * 64 + ni * 16 + lr;
    const float bn = bias[n & 1023] * bscl;
    const int h = (n >> 6) & 15, d = n & 63;
#pragma unroll
    for (int mi = 0; mi < 4; ++mi) {
      const int mb = m0 + wm * 64 + mi * 16 + lg * 4;
      f32x4 v = acc[mi][ni];
      if (z < 2) {
#pragma unroll
        for (int j = 0; j < 4; ++j) {
          int m = mb + j;
          int b = m >> 11, s = m & 2047;
          Cp[((size_t)((b * NHEAD + h) * S_LEN) + s) * HDIM + d] = f2bf(v[j] + bn);
        }
      } else {
        int b = mb >> 11, s = mb & 2047;
        s16x4 p;
#pragma unroll
        for (int j = 0; j < 4; ++j) p[j] = f2bf(v[j] + bn);
        *(s16x4*)&Cp[((size_t)((b * NHEAD + h) * HDIM) + d) * S_LEN + s] = p;
      }
    }
  }
}

// ---------------------------------------------------------------------------
// Output projection: bf16 A (attn out) @ Wto^T + bo -> fp32. grid flat 32x8.
// ---------------------------------------------------------------------------
__global__ __launch_bounds__(256) void gemm_o_k(const short* __restrict__ A,
                                                const short* __restrict__ Bt,
                                                const float* __restrict__ bias,
                                                float* __restrict__ C) {
  __shared__ short As[128 * 64];
  __shared__ short Bs[128 * 64];
  const int nwg = gridDim.x * gridDim.y;           // 256
  const int orig = blockIdx.y * gridDim.x + blockIdx.x;
  const int wg = (orig & 7) * (nwg >> 3) + (orig >> 3);
  const int m0 = (wg & 31) * 128;
  const int n0 = (wg >> 5) * 128;

  f32x4 acc[4][4] = {};
  gemm_core_bf16(A, Bt, As, Bs, m0, n0, acc);

  const int tid = threadIdx.x, lane = tid & 63, w = tid >> 6;
  const int wm = w >> 1, wn = w & 1;
  const int lr = lane & 15, lg = lane >> 4;
#pragma unroll
  for (int ni = 0; ni < 4; ++ni) {
    const int n = n0 + wn * 64 + ni * 16 + lr;
    const float bn = bias[n];
#pragma unroll
    for (int mi = 0; mi < 4; ++mi) {
      const int mb = m0 + wm * 64 + mi * 16 + lg * 4;
      f32x4 v = acc[mi][ni];
#pragma unroll
      for (int j = 0; j < 4; ++j)
        C[(size_t)(mb + j) * D_MODEL + n] = v[j] + bn;
    }
  }
}

// ---------------------------------------------------------------------------
// Flash attention (causal). grid (32,32) = 1024 blocks, one 64-row q-tile
// each, 4 waves (16 q-rows/wave). 4 blocks/CU (32 KB LDS, lb(256,4)).
//  - XCD swizzle: each XCD owns 4 whole heads -> K/V (2 MB) L2-resident.
//  - Per-CU balance: qt = (bh&1) ? qi : 31-qi pairs long/short blocks.
//  - K/V staged via global_load_lds w16 into linear [64][64] LDS, XOR
//    slot-swizzle (inverse-perm global source + swizzled ds_read).
//  - Double-buffered: issue tile t+1 loads before computing tile t.
//  - Scores arrive pre-scaled into log2 domain (Wq folded).
//  - defer-max (THR=8 log2): skip o/l rescale when max doesn't grow much.
// Q,K: [bh][2048][64] bf16; Vt: [bh][64][2048] bf16; AO: [4096][1024] bf16.
// ---------------------------------------------------------------------------
__global__ __launch_bounds__(256, 4) void attn_k(const short* __restrict__ Q,
                                                 const short* __restrict__ K,
                                                 const short* __restrict__ Vt,
                                                 short* __restrict__ AO) {
  __shared__ short Ks[2][KVB * HDIM];
  __shared__ short Vs[2][HDIM * KVB];
  const int tid = threadIdx.x, w = tid >> 6, lane = tid & 63;
  const int lr = lane & 15, lg = lane >> 4;
  const int orig = blockIdx.y * gridDim.x + blockIdx.x;
  const int wg = (orig & 7) * 128 + (orig >> 3);
  const int bh = wg >> 5, qi = wg & 31;
  const int qt = (bh & 1) ? qi : 31 - qi;
  const int q0 = qt * 64, nt = qt + 1;
  const int b = bh >> 4, h = bh & 15;
  const size_t headQK = (size_t)bh * S_LEN * HDIM;
  const size_t headV = (size_t)bh * HDIM * S_LEN;
  const int qrow = q0 + w * 16 + lr;

  const int l8 = lane >> 3, sl = lane & 7;
  const int scol = ((sl ^ l8) << 3);

  auto stage = [&](int kv0, int buf) {
#pragma unroll
    for (int j = 0; j < 2; ++j) {
      const int rb = w * 2 + j;
      const int row = rb * 8 + l8;
      gl_lds16(&K[headQK + (size_t)(kv0 + row) * HDIM + scol],
               &Ks[buf][rb * 512]);
      gl_lds16(&Vt[headV + (size_t)row * S_LEN + kv0 + scol],
               &Vs[buf][rb * 512]);
    }
  };

  const s16x8 qf0 = *(const s16x8*)&Q[headQK + (size_t)qrow * HDIM + lg * 8];
  const s16x8 qf1 = *(const s16x8*)&Q[headQK + (size_t)qrow * HDIM + 32 + lg * 8];

  f32x4 o[4] = {};
  float m_run = -1e30f, l_run = 0.f;

  stage(0, 0);
  __syncthreads();

  for (int t = 0; t < nt; ++t) {
    if (t + 1 < nt) stage((t + 1) * KVB, (t + 1) & 1);
    const short* Kc = Ks[t & 1];
    const short* Vc = Vs[t & 1];

    // scores^T (already scaled to log2 domain): S^T = K @ Q'^T
    f32x4 sc[4];
#pragma unroll
    for (int g = 0; g < 4; ++g) {
      const int R = g * 16 + lr;
      const s16x8 kf0 = *(const s16x8*)&Kc[R * 64 + ((lg ^ (lr & 7)) << 3)];
      const s16x8 kf1 = *(const s16x8*)&Kc[R * 64 + (((4 | lg) ^ (lr & 7)) << 3)];
      f32x4 z = {0.f, 0.f, 0.f, 0.f};
      sc[g] = __builtin_amdgcn_mfma_f32_16x16x32_bf16(kf0, qf0, z, 0, 0, 0);
      sc[g] = __builtin_amdgcn_mfma_f32_16x16x32_bf16(kf1, qf1, sc[g], 0, 0, 0);
    }

    if (t == nt - 1) {  // causal mask, diagonal tile only (uniform branch)
      const int kv0 = t * KVB;
#pragma unroll
      for (int g = 0; g < 4; ++g)
#pragma unroll
        for (int j = 0; j < 4; ++j)
          if (kv0 + g * 16 + lg * 4 + j > qrow) sc[g][j] = -1e30f;
    }

    // tile max (tree) + cross-lane reduce
    float mg[4];
#pragma unroll
    for (int g = 0; g < 4; ++g)
      mg[g] = fmaxf(fmaxf(sc[g][0], sc[g][1]), fmaxf(sc[g][2], sc[g][3]));
    float tm = fmaxf(fmaxf(mg[0], mg[1]), fmaxf(mg[2], mg[3]));
    tm = fmaxf(tm, __shfl_xor(tm, 16));
    tm = fmaxf(tm, __shfl_xor(tm, 32));

    // defer-max: rescale only if some row's max grew past THR=8 (=> P<=256)
    if (!__all(tm <= m_run + 8.f)) {
      const float mnew = fmaxf(m_run, tm);
      const float corr = exp2f(m_run - mnew);
      l_run *= corr;
#pragma unroll
      for (int dc = 0; dc < 4; ++dc) o[dc] = o[dc] * corr;
      m_run = mnew;
    }

    s16x4 pf[4];
    float pg[4];
#pragma unroll
    for (int g = 0; g < 4; ++g) {
      const float e0 = exp2f(sc[g][0] - m_run);
      const float e1 = exp2f(sc[g][1] - m_run);
      const float e2 = exp2f(sc[g][2] - m_run);
      const float e3 = exp2f(sc[g][3] - m_run);
      pf[g][0] = f2bf(e0); pf[g][1] = f2bf(e1);
      pf[g][2] = f2bf(e2); pf[g][3] = f2bf(e3);
      pg[g] = (e0 + e1) + (e2 + e3);
    }
    float ps = (pg[0] + pg[1]) + (pg[2] + pg[3]);
    ps += __shfl_xor(ps, 16);
    ps += __shfl_xor(ps, 32);
    l_run += ps;

#pragma unroll
    for (int g = 0; g < 4; ++g)
#pragma unroll
      for (int dc = 0; dc < 4; ++dc) {
        const int row = dc * 16 + lr;
        const s16x4 vf = *(const s16x4*)&Vc[row * 64 +
            (((2 * g + (lg >> 1)) ^ (lr & 7)) << 3) + ((lg & 1) << 2)];
        o[dc] = __builtin_amdgcn_mfma_f32_16x16x16bf16_1k(vf, pf[g], o[dc], 0, 0, 0);
      }
    __syncthreads();
  }

  const float inv = 1.f / l_run;
#pragma unroll
  for (int dc = 0; dc < 4; ++dc) {
    s16x4 pk;
#pragma unroll
    for (int j = 0; j < 4; ++j) pk[j] = f2bf(o[dc][j] * inv);
    *(s16x4*)&AO[((size_t)(b * S_LEN + qrow)) * D_MODEL + h * HDIM + dc * 16 + lg * 4] = pk;
  }
}

// ---------------------------------------------------------------------------
extern "C" void kernel_launch(void* const* d_in, const int* in_sizes, int n_in,
                              void* d_out, int out_size, void* d_ws, size_t ws_size,
                              hipStream_t stream) {
  const float* X  = (const float*)d_in[0];
  const float* Wq = (const float*)d_in[1];
  const float* bq = (const float*)d_in[2];
  const float* Wk = (const float*)d_in[3];
  const float* bk = (const float*)d_in[4];
  const float* Wv = (const float*)d_in[5];
  const float* bv = (const float*)d_in[6];
  const float* Wo = (const float*)d_in[7];
  const float* bo = (const float*)d_in[8];
  (void)in_sizes; (void)n_in; (void)out_size; (void)ws_size;

  char* ws = (char*)d_ws;
  const size_t WSZ = (size_t)D_MODEL * D_MODEL * sizeof(short);  // 2 MB
  const size_t QSZ = (size_t)M_TOT * D_MODEL * sizeof(short);    // 8 MB
  short* Wcat = (short*)ws;                       // 4 matrices, 8 MB
  short* Qb  = (short*)(ws + 4 * WSZ);
  short* Kb  = (short*)(ws + 4 * WSZ + QSZ);
  short* Vtb = (short*)(ws + 4 * WSZ + 2 * QSZ);
  short* AO  = (short*)(ws + 4 * WSZ + 3 * QSZ);  // doubles as Xb (bf16 X)
  short* Xb  = AO;  // X-cast consumed before attn writes AO
  short* Wto = Wcat + 3 * (size_t)D_MODEL * D_MODEL;

  xcast_k<<<dim3(M_TOT * D_MODEL / 2048), 256, 0, stream>>>(X, Xb);
  wtrans_k<<<dim3(32, 32, 4), dim3(32, 8), 0, stream>>>(Wq, Wk, Wv, Wo, Wcat);

  gemm_qkv_k<<<dim3(32, 24), 256, 0, stream>>>(Xb, Wcat, bq, bk, bv,
                                               Qb, Kb, Vtb);

  attn_k<<<dim3(32, 32), 256, 0, stream>>>(Qb, Kb, Vtb, AO);

  gemm_o_k<<<dim3(32, 8), 256, 0, stream>>>(AO, Wto, bo, (float*)d_out);
}

// Round 5
// 127.613 us; speedup vs baseline: 2.5373x; 1.0639x over previous
//
#include <hip/hip_runtime.h>
#include <hip/hip_bf16.h>

#define S_LEN 2048
#define D_MODEL 1024
#define NHEAD 16
#define HDIM 64
#define BATCH 2
#define M_TOT (BATCH * S_LEN)   // 4096
#define KVB 64

typedef __attribute__((ext_vector_type(4))) float f32x4;
typedef __attribute__((ext_vector_type(4))) short s16x4;
typedef __attribute__((ext_vector_type(8))) short s16x8;

#define AS1 __attribute__((address_space(1)))
#define AS3 __attribute__((address_space(3)))

#define SC2 0.18033688011112042f  // (1/8) * log2(e)

__device__ inline short f2bf(float f) {
  unsigned u = __float_as_uint(f);
  return (short)((u + 0x7fffu + ((u >> 16) & 1u)) >> 16);
}

__device__ __forceinline__ void gl_lds16(const short* g, short* l) {
  __builtin_amdgcn_global_load_lds((const AS1 void*)g, (AS3 void*)l, 16, 0, 0);
}

// ---------------------------------------------------------------------------
// X fp32 -> bf16 cast. grid 2048, block 256, 8 elems/thread.
// ---------------------------------------------------------------------------
__global__ __launch_bounds__(256) void xcast_k(const float* __restrict__ X,
                                               short* __restrict__ Xb) {
  const size_t i = ((size_t)blockIdx.x * 256 + threadIdx.x) * 8;
  float4 a = *(const float4*)&X[i];
  float4 b = *(const float4*)&X[i + 4];
  s16x8 p;
  p[0] = f2bf(a.x); p[1] = f2bf(a.y); p[2] = f2bf(a.z); p[3] = f2bf(a.w);
  p[4] = f2bf(b.x); p[5] = f2bf(b.y); p[6] = f2bf(b.z); p[7] = f2bf(b.w);
  *(s16x8*)&Xb[i] = p;
}

// ---------------------------------------------------------------------------
// Weight transpose + cast, all 4 weights into contiguous Wcat[z][n][k].
// Wq (z==0) pre-scaled by (1/8)*log2(e). grid (32,32,4), block (32,8)
// ---------------------------------------------------------------------------
__global__ __launch_bounds__(256) void wtrans_k(const float* __restrict__ W0,
                                                const float* __restrict__ W1,
                                                const float* __restrict__ W2,
                                                const float* __restrict__ W3,
                                                short* __restrict__ Wcat) {
  const int z = blockIdx.z;
  const float* W = z == 0 ? W0 : z == 1 ? W1 : z == 2 ? W2 : W3;
  short* Wt = Wcat + (size_t)z * D_MODEL * D_MODEL;
  const float scl = (z == 0) ? SC2 : 1.f;
  __shared__ float tile[32][33];
  const int tx = threadIdx.x, ty = threadIdx.y;
  const int n0 = blockIdx.x * 32, k0 = blockIdx.y * 32;
#pragma unroll
  for (int j = 0; j < 4; ++j)
    tile[ty + j * 8][tx] = W[(size_t)(k0 + ty + j * 8) * D_MODEL + n0 + tx];
  __syncthreads();
#pragma unroll
  for (int j = 0; j < 4; ++j)
    Wt[(size_t)(n0 + ty + j * 8) * D_MODEL + k0 + tx] =
        f2bf(tile[tx][ty + j * 8] * scl);
}

// ---------------------------------------------------------------------------
// GEMM core, 2-phase double-buffered (T3 minimum recipe):
//   prologue: STAGE(buf0); barrier
//   iter t:   STAGE(buf^1, t+1) issued FIRST (async, hides under MFMA)
//             ds_read frags(buf) -> 32 MFMA (setprio-wrapped)
//             one __syncthreads() (vmcnt-0 drain is short: loads had the
//             whole compute phase to complete)
// 128x128 tile, BK=64, mfma 16x16x32 bf16, 4 waves.
// global_load_lds w16 into linear LDS; XOR slot-swizzle (slot ^= row&7) as
// inverse-permuted GLOBAL source + same perm on ds_read (conflict-free).
// LDS: 2 x (16KB A + 16KB B) = 64KB -> 2 blocks/CU.
// ---------------------------------------------------------------------------
__device__ __forceinline__ void gemm_core_bf16(const short* __restrict__ A,
                                               const short* __restrict__ Bt,
                                               short* As, short* Bs,
                                               int m0, int n0,
                                               f32x4 (&acc)[4][4]) {
  const int tid = threadIdx.x;
  const int lane = tid & 63, w = tid >> 6;
  const int wm = w >> 1, wn = w & 1;
  const int lr = lane & 15, lg = lane >> 4;
  const int lr8 = lane >> 3;
  const int sl = lane & 7;
  const int scol = ((sl ^ lr8) << 3);

  auto stage = [&](int buf, int k0) {
#pragma unroll
    for (int j = 0; j < 4; ++j) {
      const int rb = j * 4 + w;
      const int row = rb * 8 + lr8;
      gl_lds16(&A[(size_t)(m0 + row) * D_MODEL + k0 + scol],
               &As[buf * 8192 + rb * 512]);
      gl_lds16(&Bt[(size_t)(n0 + row) * D_MODEL + k0 + scol],
               &Bs[buf * 8192 + rb * 512]);
    }
  };

  stage(0, 0);
  __syncthreads();

  for (int t = 0; t < D_MODEL / 64; ++t) {
    const int cur = t & 1;
    if (t + 1 < D_MODEL / 64) stage(cur ^ 1, (t + 1) * 64);
    const short* Ac = As + cur * 8192;
    const short* Bc = Bs + cur * 8192;
#pragma unroll
    for (int ks = 0; ks < 2; ++ks) {
      s16x8 af[4], bfr[4];
#pragma unroll
      for (int i = 0; i < 4; ++i) {
        const int Ra = wm * 64 + i * 16 + lr;
        const int Rb = wn * 64 + i * 16 + lr;
        af[i]  = *(const s16x8*)&Ac[Ra * 64 + ((((ks << 2) | lg) ^ (Ra & 7)) << 3)];
        bfr[i] = *(const s16x8*)&Bc[Rb * 64 + ((((ks << 2) | lg) ^ (Rb & 7)) << 3)];
      }
      __builtin_amdgcn_s_setprio(1);
#pragma unroll
      for (int mi = 0; mi < 4; ++mi)
#pragma unroll
        for (int ni = 0; ni < 4; ++ni)
          acc[mi][ni] = __builtin_amdgcn_mfma_f32_16x16x32_bf16(
              af[mi], bfr[ni], acc[mi][ni], 0, 0, 0);
      __builtin_amdgcn_s_setprio(0);
    }
    __syncthreads();
  }
}

// ---------------------------------------------------------------------------
// Fused QKV projection: one GEMM, N = 3072 (Wq|Wk|Wv rows concatenated).
// grid 768 (1D). XCD-bijective swizzle, then n-FASTEST mapping within each
// XCD chunk: each XCD's 96 blocks = 4 A-panels (1 MB, L2-resident) x 24 n.
// z = n0>>10 routes output: z<2 -> [b,h,s,d]; z==2 -> V transposed [b,h,d,s].
// ---------------------------------------------------------------------------
__global__ __launch_bounds__(256) void gemm_qkv_k(
    const short* __restrict__ Xb, const short* __restrict__ Wcat,
    const float* __restrict__ bq, const float* __restrict__ bk,
    const float* __restrict__ bv, short* __restrict__ Qb,
    short* __restrict__ Kb, short* __restrict__ Vtb) {
  __shared__ short As[2 * 128 * 64];
  __shared__ short Bs[2 * 128 * 64];
  const int orig = blockIdx.x;                 // 768 = 96 per XCD
  const int wg = (orig & 7) * 96 + (orig >> 3);
  const int m0 = (wg / 24) * 128;              // n-fastest within chunk
  const int n0 = (wg % 24) * 128;

  f32x4 acc[4][4] = {};
  gemm_core_bf16(Xb, Wcat, As, Bs, m0, n0, acc);

  const int z = n0 >> 10;
  const float* bias = z == 0 ? bq : z == 1 ? bk : bv;
  short* Cp = z == 0 ? Qb : z == 1 ? Kb : Vtb;
  const float bscl = (z == 0) ? SC2 : 1.f;

  const int tid = threadIdx.x, lane = tid & 63, w = tid >> 6;
  const int wm = w >> 1, wn = w & 1;
  const int lr = lane & 15, lg = lane >> 4;
#pragma unroll
  for (int ni = 0; ni < 4; ++ni) {
    const int n = n0 + wn * 64 + ni * 16 + lr;
    const float bn = bias[n & 1023] * bscl;
    const int h = (n >> 6) & 15, d = n & 63;
#pragma unroll
    for (int mi = 0; mi < 4; ++mi) {
      const int mb = m0 + wm * 64 + mi * 16 + lg * 4;
      f32x4 v = acc[mi][ni];
      if (z < 2) {
#pragma unroll
        for (int j = 0; j < 4; ++j) {
          int m = mb + j;
          int b = m >> 11, s = m & 2047;
          Cp[((size_t)((b * NHEAD + h) * S_LEN) + s) * HDIM + d] = f2bf(v[j] + bn);
        }
      } else {
        int b = mb >> 11, s = mb & 2047;
        s16x4 p;
#pragma unroll
        for (int j = 0; j < 4; ++j) p[j] = f2bf(v[j] + bn);
        *(s16x4*)&Cp[((size_t)((b * NHEAD + h) * HDIM) + d) * S_LEN + s] = p;
      }
    }
  }
}

// ---------------------------------------------------------------------------
// Output projection: bf16 A (attn out) @ Wto^T + bo -> fp32. grid 256 (1D).
// n-fastest within XCD chunk: 4 A-panels (1 MB) + full B (2 MB) per XCD.
// ---------------------------------------------------------------------------
__global__ __launch_bounds__(256) void gemm_o_k(const short* __restrict__ A,
                                                const short* __restrict__ Bt,
                                                const float* __restrict__ bias,
                                                float* __restrict__ C) {
  __shared__ short As[2 * 128 * 64];
  __shared__ short Bs[2 * 128 * 64];
  const int orig = blockIdx.x;                 // 256 = 32 per XCD
  const int wg = (orig & 7) * 32 + (orig >> 3);
  const int m0 = (wg >> 3) * 128;              // n-fastest within chunk
  const int n0 = (wg & 7) * 128;

  f32x4 acc[4][4] = {};
  gemm_core_bf16(A, Bt, As, Bs, m0, n0, acc);

  const int tid = threadIdx.x, lane = tid & 63, w = tid >> 6;
  const int wm = w >> 1, wn = w & 1;
  const int lr = lane & 15, lg = lane >> 4;
#pragma unroll
  for (int ni = 0; ni < 4; ++ni) {
    const int n = n0 + wn * 64 + ni * 16 + lr;
    const float bn = bias[n];
#pragma unroll
    for (int mi = 0; mi < 4; ++mi) {
      const int mb = m0 + wm * 64 + mi * 16 + lg * 4;
      f32x4 v = acc[mi][ni];
#pragma unroll
      for (int j = 0; j < 4; ++j)
        C[(size_t)(mb + j) * D_MODEL + n] = v[j] + bn;
    }
  }
}

// ---------------------------------------------------------------------------
// Flash attention (causal). grid (32,32) = 1024 blocks, one 64-row q-tile
// each, 4 waves (16 q-rows/wave). 4 blocks/CU (32 KB LDS, lb(256,4)).
// (unchanged from round 4 — already 2-phase staged)
// ---------------------------------------------------------------------------
__global__ __launch_bounds__(256, 4) void attn_k(const short* __restrict__ Q,
                                                 const short* __restrict__ K,
                                                 const short* __restrict__ Vt,
                                                 short* __restrict__ AO) {
  __shared__ short Ks[2][KVB * HDIM];
  __shared__ short Vs[2][HDIM * KVB];
  const int tid = threadIdx.x, w = tid >> 6, lane = tid & 63;
  const int lr = lane & 15, lg = lane >> 4;
  const int orig = blockIdx.y * gridDim.x + blockIdx.x;
  const int wg = (orig & 7) * 128 + (orig >> 3);
  const int bh = wg >> 5, qi = wg & 31;
  const int qt = (bh & 1) ? qi : 31 - qi;
  const int q0 = qt * 64, nt = qt + 1;
  const int b = bh >> 4, h = bh & 15;
  const size_t headQK = (size_t)bh * S_LEN * HDIM;
  const size_t headV = (size_t)bh * HDIM * S_LEN;
  const int qrow = q0 + w * 16 + lr;

  const int l8 = lane >> 3, sl = lane & 7;
  const int scol = ((sl ^ l8) << 3);

  auto stage = [&](int kv0, int buf) {
#pragma unroll
    for (int j = 0; j < 2; ++j) {
      const int rb = w * 2 + j;
      const int row = rb * 8 + l8;
      gl_lds16(&K[headQK + (size_t)(kv0 + row) * HDIM + scol],
               &Ks[buf][rb * 512]);
      gl_lds16(&Vt[headV + (size_t)row * S_LEN + kv0 + scol],
               &Vs[buf][rb * 512]);
    }
  };

  const s16x8 qf0 = *(const s16x8*)&Q[headQK + (size_t)qrow * HDIM + lg * 8];
  const s16x8 qf1 = *(const s16x8*)&Q[headQK + (size_t)qrow * HDIM + 32 + lg * 8];

  f32x4 o[4] = {};
  float m_run = -1e30f, l_run = 0.f;

  stage(0, 0);
  __syncthreads();

  for (int t = 0; t < nt; ++t) {
    if (t + 1 < nt) stage((t + 1) * KVB, (t + 1) & 1);
    const short* Kc = Ks[t & 1];
    const short* Vc = Vs[t & 1];

    // scores^T (already scaled to log2 domain): S^T = K @ Q'^T
    f32x4 sc[4];
#pragma unroll
    for (int g = 0; g < 4; ++g) {
      const int R = g * 16 + lr;
      const s16x8 kf0 = *(const s16x8*)&Kc[R * 64 + ((lg ^ (lr & 7)) << 3)];
      const s16x8 kf1 = *(const s16x8*)&Kc[R * 64 + (((4 | lg) ^ (lr & 7)) << 3)];
      f32x4 z = {0.f, 0.f, 0.f, 0.f};
      sc[g] = __builtin_amdgcn_mfma_f32_16x16x32_bf16(kf0, qf0, z, 0, 0, 0);
      sc[g] = __builtin_amdgcn_mfma_f32_16x16x32_bf16(kf1, qf1, sc[g], 0, 0, 0);
    }

    if (t == nt - 1) {  // causal mask, diagonal tile only (uniform branch)
      const int kv0 = t * KVB;
#pragma unroll
      for (int g = 0; g < 4; ++g)
#pragma unroll
        for (int j = 0; j < 4; ++j)
          if (kv0 + g * 16 + lg * 4 + j > qrow) sc[g][j] = -1e30f;
    }

    float mg[4];
#pragma unroll
    for (int g = 0; g < 4; ++g)
      mg[g] = fmaxf(fmaxf(sc[g][0], sc[g][1]), fmaxf(sc[g][2], sc[g][3]));
    float tm = fmaxf(fmaxf(mg[0], mg[1]), fmaxf(mg[2], mg[3]));
    tm = fmaxf(tm, __shfl_xor(tm, 16));
    tm = fmaxf(tm, __shfl_xor(tm, 32));

    // defer-max: rescale only if some row's max grew past THR=8 (=> P<=256)
    if (!__all(tm <= m_run + 8.f)) {
      const float mnew = fmaxf(m_run, tm);
      const float corr = exp2f(m_run - mnew);
      l_run *= corr;
#pragma unroll
      for (int dc = 0; dc < 4; ++dc) o[dc] = o[dc] * corr;
      m_run = mnew;
    }

    s16x4 pf[4];
    float pg[4];
#pragma unroll
    for (int g = 0; g < 4; ++g) {
      const float e0 = exp2f(sc[g][0] - m_run);
      const float e1 = exp2f(sc[g][1] - m_run);
      const float e2 = exp2f(sc[g][2] - m_run);
      const float e3 = exp2f(sc[g][3] - m_run);
      pf[g][0] = f2bf(e0); pf[g][1] = f2bf(e1);
      pf[g][2] = f2bf(e2); pf[g][3] = f2bf(e3);
      pg[g] = (e0 + e1) + (e2 + e3);
    }
    float ps = (pg[0] + pg[1]) + (pg[2] + pg[3]);
    ps += __shfl_xor(ps, 16);
    ps += __shfl_xor(ps, 32);
    l_run += ps;

#pragma unroll
    for (int g = 0; g < 4; ++g)
#pragma unroll
      for (int dc = 0; dc < 4; ++dc) {
        const int row = dc * 16 + lr;
        const s16x4 vf = *(const s16x4*)&Vc[row * 64 +
            (((2 * g + (lg >> 1)) ^ (lr & 7)) << 3) + ((lg & 1) << 2)];
        o[dc] = __builtin_amdgcn_mfma_f32_16x16x16bf16_1k(vf, pf[g], o[dc], 0, 0, 0);
      }
    __syncthreads();
  }

  const float inv = 1.f / l_run;
#pragma unroll
  for (int dc = 0; dc < 4; ++dc) {
    s16x4 pk;
#pragma unroll
    for (int j = 0; j < 4; ++j) pk[j] = f2bf(o[dc][j] * inv);
    *(s16x4*)&AO[((size_t)(b * S_LEN + qrow)) * D_MODEL + h * HDIM + dc * 16 + lg * 4] = pk;
  }
}

// ---------------------------------------------------------------------------
extern "C" void kernel_launch(void* const* d_in, const int* in_sizes, int n_in,
                              void* d_out, int out_size, void* d_ws, size_t ws_size,
                              hipStream_t stream) {
  const float* X  = (const float*)d_in[0];
  const float* Wq = (const float*)d_in[1];
  const float* bq = (const float*)d_in[2];
  const float* Wk = (const float*)d_in[3];
  const float* bk = (const float*)d_in[4];
  const float* Wv = (const float*)d_in[5];
  const float* bv = (const float*)d_in[6];
  const float* Wo = (const float*)d_in[7];
  const float* bo = (const float*)d_in[8];
  (void)in_sizes; (void)n_in; (void)out_size; (void)ws_size;

  char* ws = (char*)d_ws;
  const size_t WSZ = (size_t)D_MODEL * D_MODEL * sizeof(short);  // 2 MB
  const size_t QSZ = (size_t)M_TOT * D_MODEL * sizeof(short);    // 8 MB
  short* Wcat = (short*)ws;                       // 4 matrices, 8 MB
  short* Qb  = (short*)(ws + 4 * WSZ);
  short* Kb  = (short*)(ws + 4 * WSZ + QSZ);
  short* Vtb = (short*)(ws + 4 * WSZ + 2 * QSZ);
  short* AO  = (short*)(ws + 4 * WSZ + 3 * QSZ);  // doubles as Xb (bf16 X)
  short* Xb  = AO;  // X-cast consumed before attn writes AO
  short* Wto = Wcat + 3 * (size_t)D_MODEL * D_MODEL;

  xcast_k<<<dim3(M_TOT * D_MODEL / 2048), 256, 0, stream>>>(X, Xb);
  wtrans_k<<<dim3(32, 32, 4), dim3(32, 8), 0, stream>>>(Wq, Wk, Wv, Wo, Wcat);

  gemm_qkv_k<<<dim3(768), 256, 0, stream>>>(Xb, Wcat, bq, bk, bv,
                                            Qb, Kb, Vtb);

  attn_k<<<dim3(32, 32), 256, 0, stream>>>(Qb, Kb, Vtb, AO);

  gemm_o_k<<<dim3(256), 256, 0, stream>>>(AO, Wto, bo, (float*)d_out);
}

// Round 6
// 125.023 us; speedup vs baseline: 2.5899x; 1.0207x over previous
//
#include <hip/hip_runtime.h>
#include <hip/hip_bf16.h>

#define S_LEN 2048
#define D_MODEL 1024
#define NHEAD 16
#define HDIM 64
#define BATCH 2
#define M_TOT (BATCH * S_LEN)   // 4096
#define KVB 64

typedef __attribute__((ext_vector_type(4))) float f32x4;
typedef __attribute__((ext_vector_type(4))) short s16x4;
typedef __attribute__((ext_vector_type(8))) short s16x8;

#define AS1 __attribute__((address_space(1)))
#define AS3 __attribute__((address_space(3)))

#define SC2 0.18033688011112042f  // (1/8) * log2(e)

__device__ inline short f2bf(float f) {
  unsigned u = __float_as_uint(f);
  return (short)((u + 0x7fffu + ((u >> 16) & 1u)) >> 16);
}

// HW packed f32->bf16 (RNE). No builtin on gfx950 -> inline asm (T12 recipe).
__device__ __forceinline__ unsigned cvtpk(float lo, float hi) {
  unsigned r;
  asm("v_cvt_pk_bf16_f32 %0, %1, %2" : "=v"(r) : "v"(lo), "v"(hi));
  return r;
}
__device__ __forceinline__ s16x4 pk4(float a, float b, float c, float d) {
  union { unsigned u[2]; s16x4 s; } x;
  x.u[0] = cvtpk(a, b);
  x.u[1] = cvtpk(c, d);
  return x.s;
}

__device__ __forceinline__ void gl_lds16(const short* g, short* l) {
  __builtin_amdgcn_global_load_lds((const AS1 void*)g, (AS3 void*)l, 16, 0, 0);
}

// ---------------------------------------------------------------------------
// X fp32 -> bf16 cast. grid 2048, block 256, 8 elems/thread.
// ---------------------------------------------------------------------------
__global__ __launch_bounds__(256) void xcast_k(const float* __restrict__ X,
                                               short* __restrict__ Xb) {
  const size_t i = ((size_t)blockIdx.x * 256 + threadIdx.x) * 8;
  float4 a = *(const float4*)&X[i];
  float4 b = *(const float4*)&X[i + 4];
  s16x8 p;
  p[0] = f2bf(a.x); p[1] = f2bf(a.y); p[2] = f2bf(a.z); p[3] = f2bf(a.w);
  p[4] = f2bf(b.x); p[5] = f2bf(b.y); p[6] = f2bf(b.z); p[7] = f2bf(b.w);
  *(s16x8*)&Xb[i] = p;
}

// ---------------------------------------------------------------------------
// Weight transpose + cast, all 4 weights into contiguous Wcat[z][n][k].
// Wq (z==0) pre-scaled by (1/8)*log2(e). grid (32,32,4), block (32,8)
// ---------------------------------------------------------------------------
__global__ __launch_bounds__(256) void wtrans_k(const float* __restrict__ W0,
                                                const float* __restrict__ W1,
                                                const float* __restrict__ W2,
                                                const float* __restrict__ W3,
                                                short* __restrict__ Wcat) {
  const int z = blockIdx.z;
  const float* W = z == 0 ? W0 : z == 1 ? W1 : z == 2 ? W2 : W3;
  short* Wt = Wcat + (size_t)z * D_MODEL * D_MODEL;
  const float scl = (z == 0) ? SC2 : 1.f;
  __shared__ float tile[32][33];
  const int tx = threadIdx.x, ty = threadIdx.y;
  const int n0 = blockIdx.x * 32, k0 = blockIdx.y * 32;
#pragma unroll
  for (int j = 0; j < 4; ++j)
    tile[ty + j * 8][tx] = W[(size_t)(k0 + ty + j * 8) * D_MODEL + n0 + tx];
  __syncthreads();
#pragma unroll
  for (int j = 0; j < 4; ++j)
    Wt[(size_t)(n0 + ty + j * 8) * D_MODEL + k0 + tx] =
        f2bf(tile[tx][ty + j * 8] * scl);
}

// ---------------------------------------------------------------------------
// GEMM core, 2-phase double-buffered (unchanged from round 5).
// ---------------------------------------------------------------------------
__device__ __forceinline__ void gemm_core_bf16(const short* __restrict__ A,
                                               const short* __restrict__ Bt,
                                               short* As, short* Bs,
                                               int m0, int n0,
                                               f32x4 (&acc)[4][4]) {
  const int tid = threadIdx.x;
  const int lane = tid & 63, w = tid >> 6;
  const int wm = w >> 1, wn = w & 1;
  const int lr = lane & 15, lg = lane >> 4;
  const int lr8 = lane >> 3;
  const int sl = lane & 7;
  const int scol = ((sl ^ lr8) << 3);

  auto stage = [&](int buf, int k0) {
#pragma unroll
    for (int j = 0; j < 4; ++j) {
      const int rb = j * 4 + w;
      const int row = rb * 8 + lr8;
      gl_lds16(&A[(size_t)(m0 + row) * D_MODEL + k0 + scol],
               &As[buf * 8192 + rb * 512]);
      gl_lds16(&Bt[(size_t)(n0 + row) * D_MODEL + k0 + scol],
               &Bs[buf * 8192 + rb * 512]);
    }
  };

  stage(0, 0);
  __syncthreads();

  for (int t = 0; t < D_MODEL / 64; ++t) {
    const int cur = t & 1;
    if (t + 1 < D_MODEL / 64) stage(cur ^ 1, (t + 1) * 64);
    const short* Ac = As + cur * 8192;
    const short* Bc = Bs + cur * 8192;
#pragma unroll
    for (int ks = 0; ks < 2; ++ks) {
      s16x8 af[4], bfr[4];
#pragma unroll
      for (int i = 0; i < 4; ++i) {
        const int Ra = wm * 64 + i * 16 + lr;
        const int Rb = wn * 64 + i * 16 + lr;
        af[i]  = *(const s16x8*)&Ac[Ra * 64 + ((((ks << 2) | lg) ^ (Ra & 7)) << 3)];
        bfr[i] = *(const s16x8*)&Bc[Rb * 64 + ((((ks << 2) | lg) ^ (Rb & 7)) << 3)];
      }
      __builtin_amdgcn_s_setprio(1);
#pragma unroll
      for (int mi = 0; mi < 4; ++mi)
#pragma unroll
        for (int ni = 0; ni < 4; ++ni)
          acc[mi][ni] = __builtin_amdgcn_mfma_f32_16x16x32_bf16(
              af[mi], bfr[ni], acc[mi][ni], 0, 0, 0);
      __builtin_amdgcn_s_setprio(0);
    }
    __syncthreads();
  }
}

// ---------------------------------------------------------------------------
// Fused QKV projection (unchanged from round 5).
// ---------------------------------------------------------------------------
__global__ __launch_bounds__(256) void gemm_qkv_k(
    const short* __restrict__ Xb, const short* __restrict__ Wcat,
    const float* __restrict__ bq, const float* __restrict__ bk,
    const float* __restrict__ bv, short* __restrict__ Qb,
    short* __restrict__ Kb, short* __restrict__ Vtb) {
  __shared__ short As[2 * 128 * 64];
  __shared__ short Bs[2 * 128 * 64];
  const int orig = blockIdx.x;                 // 768 = 96 per XCD
  const int wg = (orig & 7) * 96 + (orig >> 3);
  const int m0 = (wg / 24) * 128;              // n-fastest within chunk
  const int n0 = (wg % 24) * 128;

  f32x4 acc[4][4] = {};
  gemm_core_bf16(Xb, Wcat, As, Bs, m0, n0, acc);

  const int z = n0 >> 10;
  const float* bias = z == 0 ? bq : z == 1 ? bk : bv;
  short* Cp = z == 0 ? Qb : z == 1 ? Kb : Vtb;
  const float bscl = (z == 0) ? SC2 : 1.f;

  const int tid = threadIdx.x, lane = tid & 63, w = tid >> 6;
  const int wm = w >> 1, wn = w & 1;
  const int lr = lane & 15, lg = lane >> 4;
#pragma unroll
  for (int ni = 0; ni < 4; ++ni) {
    const int n = n0 + wn * 64 + ni * 16 + lr;
    const float bn = bias[n & 1023] * bscl;
    const int h = (n >> 6) & 15, d = n & 63;
#pragma unroll
    for (int mi = 0; mi < 4; ++mi) {
      const int mb = m0 + wm * 64 + mi * 16 + lg * 4;
      f32x4 v = acc[mi][ni];
      if (z < 2) {
#pragma unroll
        for (int j = 0; j < 4; ++j) {
          int m = mb + j;
          int b = m >> 11, s = m & 2047;
          Cp[((size_t)((b * NHEAD + h) * S_LEN) + s) * HDIM + d] = f2bf(v[j] + bn);
        }
      } else {
        int b = mb >> 11, s = mb & 2047;
        s16x4 p;
#pragma unroll
        for (int j = 0; j < 4; ++j) p[j] = f2bf(v[j] + bn);
        *(s16x4*)&Cp[((size_t)((b * NHEAD + h) * HDIM) + d) * S_LEN + s] = p;
      }
    }
  }
}

// ---------------------------------------------------------------------------
// Output projection (unchanged from round 5).
// ---------------------------------------------------------------------------
__global__ __launch_bounds__(256) void gemm_o_k(const short* __restrict__ A,
                                                const short* __restrict__ Bt,
                                                const float* __restrict__ bias,
                                                float* __restrict__ C) {
  __shared__ short As[2 * 128 * 64];
  __shared__ short Bs[2 * 128 * 64];
  const int orig = blockIdx.x;                 // 256 = 32 per XCD
  const int wg = (orig & 7) * 32 + (orig >> 3);
  const int m0 = (wg >> 3) * 128;              // n-fastest within chunk
  const int n0 = (wg & 7) * 128;

  f32x4 acc[4][4] = {};
  gemm_core_bf16(A, Bt, As, Bs, m0, n0, acc);

  const int tid = threadIdx.x, lane = tid & 63, w = tid >> 6;
  const int wm = w >> 1, wn = w & 1;
  const int lr = lane & 15, lg = lane >> 4;
#pragma unroll
  for (int ni = 0; ni < 4; ++ni) {
    const int n = n0 + wn * 64 + ni * 16 + lr;
    const float bn = bias[n];
#pragma unroll
    for (int mi = 0; mi < 4; ++mi) {
      const int mb = m0 + wm * 64 + mi * 16 + lg * 4;
      f32x4 v = acc[mi][ni];
#pragma unroll
      for (int j = 0; j < 4; ++j)
        C[(size_t)(mb + j) * D_MODEL + n] = v[j] + bn;
    }
  }
}

// ---------------------------------------------------------------------------
// Flash attention (causal). grid (32,32) = 1024 blocks, one 64-row q-tile
// each, 4 waves (16 q-rows/wave).
// Round-6 softmax restructure (common path has ZERO cross-lane DS ops):
//  - per-lane partial l, reduced across lane-groups ONCE at the end
//  - defer-max test on per-lane max (1 ballot); full row-max reduce +
//    rescale only when triggered (rare, THR=8 in log2 domain)
//  - P packing via HW v_cvt_pk_bf16_f32 (8 insts vs ~48 software f2bf)
//  - setprio(1) around MFMA clusters (T5, attn-positive)
// ---------------------------------------------------------------------------
__global__ __launch_bounds__(256, 4) void attn_k(const short* __restrict__ Q,
                                                 const short* __restrict__ K,
                                                 const short* __restrict__ Vt,
                                                 short* __restrict__ AO) {
  __shared__ short Ks[2][KVB * HDIM];
  __shared__ short Vs[2][HDIM * KVB];
  const int tid = threadIdx.x, w = tid >> 6, lane = tid & 63;
  const int lr = lane & 15, lg = lane >> 4;
  const int orig = blockIdx.y * gridDim.x + blockIdx.x;
  const int wg = (orig & 7) * 128 + (orig >> 3);
  const int bh = wg >> 5, qi = wg & 31;
  const int qt = (bh & 1) ? qi : 31 - qi;
  const int q0 = qt * 64, nt = qt + 1;
  const int b = bh >> 4, h = bh & 15;
  const size_t headQK = (size_t)bh * S_LEN * HDIM;
  const size_t headV = (size_t)bh * HDIM * S_LEN;
  const int qrow = q0 + w * 16 + lr;

  const int l8 = lane >> 3, sl = lane & 7;
  const int scol = ((sl ^ l8) << 3);

  auto stage = [&](int kv0, int buf) {
#pragma unroll
    for (int j = 0; j < 2; ++j) {
      const int rb = w * 2 + j;
      const int row = rb * 8 + l8;
      gl_lds16(&K[headQK + (size_t)(kv0 + row) * HDIM + scol],
               &Ks[buf][rb * 512]);
      gl_lds16(&Vt[headV + (size_t)row * S_LEN + kv0 + scol],
               &Vs[buf][rb * 512]);
    }
  };

  const s16x8 qf0 = *(const s16x8*)&Q[headQK + (size_t)qrow * HDIM + lg * 8];
  const s16x8 qf1 = *(const s16x8*)&Q[headQK + (size_t)qrow * HDIM + 32 + lg * 8];

  f32x4 o[4] = {};
  float m_run = -1e30f;
  float l_part = 0.f;   // per-lane partial; cross-lane reduced once at end

  stage(0, 0);
  __syncthreads();

  for (int t = 0; t < nt; ++t) {
    if (t + 1 < nt) stage((t + 1) * KVB, (t + 1) & 1);
    const short* Kc = Ks[t & 1];
    const short* Vc = Vs[t & 1];

    // scores^T (already scaled to log2 domain): S^T = K @ Q'^T
    f32x4 sc[4];
    __builtin_amdgcn_s_setprio(1);
#pragma unroll
    for (int g = 0; g < 4; ++g) {
      const int R = g * 16 + lr;
      const s16x8 kf0 = *(const s16x8*)&Kc[R * 64 + ((lg ^ (lr & 7)) << 3)];
      const s16x8 kf1 = *(const s16x8*)&Kc[R * 64 + (((4 | lg) ^ (lr & 7)) << 3)];
      f32x4 z = {0.f, 0.f, 0.f, 0.f};
      sc[g] = __builtin_amdgcn_mfma_f32_16x16x32_bf16(kf0, qf0, z, 0, 0, 0);
      sc[g] = __builtin_amdgcn_mfma_f32_16x16x32_bf16(kf1, qf1, sc[g], 0, 0, 0);
    }
    __builtin_amdgcn_s_setprio(0);

    if (t == nt - 1) {  // causal mask, diagonal tile only (uniform branch)
      const int kv0 = t * KVB;
#pragma unroll
      for (int g = 0; g < 4; ++g)
#pragma unroll
        for (int j = 0; j < 4; ++j)
          if (kv0 + g * 16 + lg * 4 + j > qrow) sc[g][j] = -1e30f;
    }

    // per-lane max over this lane's 16 P values (no cross-lane in common path)
    float mg[4];
#pragma unroll
    for (int g = 0; g < 4; ++g)
      mg[g] = fmaxf(fmaxf(sc[g][0], sc[g][1]), fmaxf(sc[g][2], sc[g][3]));
    const float tm = fmaxf(fmaxf(mg[0], mg[1]), fmaxf(mg[2], mg[3]));

    // defer-max: full row-max reduce + rescale only when some row grew >THR=8
    if (!__all(tm <= m_run + 8.f)) {
      float tr = fmaxf(tm, m_run);
      tr = fmaxf(tr, __shfl_xor(tr, 16));
      tr = fmaxf(tr, __shfl_xor(tr, 32));
      const float corr = exp2f(m_run - tr);
      l_part *= corr;
#pragma unroll
      for (int dc = 0; dc < 4; ++dc) o[dc] = o[dc] * corr;
      m_run = tr;
    }

    // P = exp2(sc - m_run), pack via HW cvt_pk, accumulate per-lane l
    s16x4 pf[4];
#pragma unroll
    for (int g = 0; g < 4; ++g) {
      const float e0 = exp2f(sc[g][0] - m_run);
      const float e1 = exp2f(sc[g][1] - m_run);
      const float e2 = exp2f(sc[g][2] - m_run);
      const float e3 = exp2f(sc[g][3] - m_run);
      pf[g] = pk4(e0, e1, e2, e3);
      l_part += (e0 + e1) + (e2 + e3);
    }

    __builtin_amdgcn_s_setprio(1);
#pragma unroll
    for (int g = 0; g < 4; ++g)
#pragma unroll
      for (int dc = 0; dc < 4; ++dc) {
        const int row = dc * 16 + lr;
        const s16x4 vf = *(const s16x4*)&Vc[row * 64 +
            (((2 * g + (lg >> 1)) ^ (lr & 7)) << 3) + ((lg & 1) << 2)];
        o[dc] = __builtin_amdgcn_mfma_f32_16x16x16bf16_1k(vf, pf[g], o[dc], 0, 0, 0);
      }
    __builtin_amdgcn_s_setprio(0);
    __syncthreads();
  }

  // single end-of-tile cross-lane reduce of the partial l (lanes of same row)
  float lt = l_part;
  lt += __shfl_xor(lt, 16);
  lt += __shfl_xor(lt, 32);
  const float inv = 1.f / lt;
#pragma unroll
  for (int dc = 0; dc < 4; ++dc) {
    s16x4 pk;
#pragma unroll
    for (int j = 0; j < 4; ++j) pk[j] = f2bf(o[dc][j] * inv);
    *(s16x4*)&AO[((size_t)(b * S_LEN + qrow)) * D_MODEL + h * HDIM + dc * 16 + lg * 4] = pk;
  }
}

// ---------------------------------------------------------------------------
extern "C" void kernel_launch(void* const* d_in, const int* in_sizes, int n_in,
                              void* d_out, int out_size, void* d_ws, size_t ws_size,
                              hipStream_t stream) {
  const float* X  = (const float*)d_in[0];
  const float* Wq = (const float*)d_in[1];
  const float* bq = (const float*)d_in[2];
  const float* Wk = (const float*)d_in[3];
  const float* bk = (const float*)d_in[4];
  const float* Wv = (const float*)d_in[5];
  const float* bv = (const float*)d_in[6];
  const float* Wo = (const float*)d_in[7];
  const float* bo = (const float*)d_in[8];
  (void)in_sizes; (void)n_in; (void)out_size; (void)ws_size;

  char* ws = (char*)d_ws;
  const size_t WSZ = (size_t)D_MODEL * D_MODEL * sizeof(short);  // 2 MB
  const size_t QSZ = (size_t)M_TOT * D_MODEL * sizeof(short);    // 8 MB
  short* Wcat = (short*)ws;                       // 4 matrices, 8 MB
  short* Qb  = (short*)(ws + 4 * WSZ);
  short* Kb  = (short*)(ws + 4 * WSZ + QSZ);
  short* Vtb = (short*)(ws + 4 * WSZ + 2 * QSZ);
  short* AO  = (short*)(ws + 4 * WSZ + 3 * QSZ);  // doubles as Xb (bf16 X)
  short* Xb  = AO;  // X-cast consumed before attn writes AO
  short* Wto = Wcat + 3 * (size_t)D_MODEL * D_MODEL;

  xcast_k<<<dim3(M_TOT * D_MODEL / 2048), 256, 0, stream>>>(X, Xb);
  wtrans_k<<<dim3(32, 32, 4), dim3(32, 8), 0, stream>>>(Wq, Wk, Wv, Wo, Wcat);

  gemm_qkv_k<<<dim3(768), 256, 0, stream>>>(Xb, Wcat, bq, bk, bv,
                                            Qb, Kb, Vtb);

  attn_k<<<dim3(32, 32), 256, 0, stream>>>(Qb, Kb, Vtb, AO);

  gemm_o_k<<<dim3(256), 256, 0, stream>>>(AO, Wto, bo, (float*)d_out);
}